// Round 1
// baseline (1124.032 us; speedup 1.0000x reference)
//
#include <hip/hip_runtime.h>
#include <math.h>

#define VV 2048
#define BIGC 1e9f

__device__ __forceinline__ float wsum64(float v){
  v += __shfl_xor(v, 1, 64);
  v += __shfl_xor(v, 2, 64);
  v += __shfl_xor(v, 4, 64);
  v += __shfl_xor(v, 8, 64);
  v += __shfl_xor(v, 16, 64);
  v += __shfl_xor(v, 32, 64);
  return v;
}
__device__ __forceinline__ float sigm(float x){ return 1.f/(1.f+expf(-x)); }

// ---------------- K_zero: zero the 8 output floats ----------------
__global__ void k_zero(float* out){
  if(threadIdx.x < 8) out[threadIdx.x] = 0.f;
}

// ---------------- K0: per-node encoder + layer-1 precomputes ----------------
// one wave per (b,u) row
__global__ void k_enc(const float* __restrict__ feat, const float* __restrict__ emb,
                      const float* __restrict__ encW, const float* __restrict__ encb,
                      const float* __restrict__ gatW, const float* __restrict__ gatb,
                      const float* __restrict__ gata, const float* __restrict__ gruWh,
                      float* __restrict__ enc, float* __restrict__ He,
                      float* __restrict__ sHe, float* __restrict__ Hh1)
{
  __shared__ float L[4][112];
  int wid = threadIdx.x >> 6, lane = threadIdx.x & 63;
  int row = blockIdx.x*4 + wid;        // b*V + u
  int u = row & (VV-1);
  // emb norm clip
  float ev = (lane < 32) ? emb[u*32 + lane] : 0.f;
  float ss = wsum64(ev*ev);
  float nrm = sqrtf(ss);
  float scale = (nrm > 1.f) ? 1.f/nrm : 1.f;
  if(lane < 32) L[wid][lane] = ev*scale;
  else if(lane < 48) L[wid][lane] = feat[row*16 + (lane-32)];
  __syncthreads();
  float e = encb[lane];
  #pragma unroll
  for(int k=0;k<48;k++) e += L[wid][k]*encW[k*64+lane];
  enc[row*64+lane] = e;
  L[wid][48+lane] = e;
  __syncthreads();
  float h = gatb[lane];
  for(int k=0;k<64;k++) h += L[wid][48+k]*gatW[k*64+lane];
  h = tanhf(h);
  He[row*64+lane] = h;
  float s = wsum64(h*gata[lane]);
  if(lane==0) sHe[row] = s;
  for(int j=0;j<3;j++){
    float acc = 0.f;
    for(int k=0;k<64;k++) acc += L[wid][48+k]*gruWh[k*192 + 64*j + lane];
    Hh1[row*192 + 64*j + lane] = acc;
  }
}

// ---------------- K1: layer-1 GAT agg + Yx1 = (agg1+enc)@Wx ----------------
__global__ void k_agg1(const float* __restrict__ enc, const float* __restrict__ He,
                       const float* __restrict__ sHe,
                       const float* __restrict__ gatb, const float* __restrict__ gata,
                       const float* __restrict__ gruWx,
                       const int* __restrict__ adj, const int* __restrict__ num_nodes,
                       float* __restrict__ Yx1)
{
  __shared__ float L[4][64];
  int wid = threadIdx.x>>6, lane = threadIdx.x & 63;
  int row = blockIdx.x*4 + wid;
  int b = row >> 11;
  int nn = num_nodes[b];
  float tb = tanhf(gatb[lane]);           // h row for masked (state=0)
  float cs = wsum64(tb*gata[lane]);
  float hrow[16]; float sc[16];
  #pragma unroll
  for(int d=0; d<16; d++){
    int a = adj[row*16+d];
    bool m = (a==nn);
    int arow = (b<<11) + a;
    hrow[d] = m ? tb : He[arow*64+lane];
    sc[d]   = m ? (cs - BIGC) : sHe[arow];
  }
  float mx = sc[0];
  #pragma unroll
  for(int d=1;d<16;d++) mx = fmaxf(mx, sc[d]);
  float den = 0.f;
  #pragma unroll
  for(int d=0;d<16;d++){ sc[d] = expf(sc[d]-mx); den += sc[d]; }
  float invd = 1.f/den;
  float agg = 0.f;
  #pragma unroll
  for(int d=0;d<16;d++) agg += sc[d]*invd*hrow[d];
  L[wid][lane] = agg + enc[row*64+lane];
  __syncthreads();
  for(int j=0;j<3;j++){
    float acc = 0.f;
    for(int k=0;k<64;k++) acc += L[wid][k]*gruWx[k*192+64*j+lane];
    Yx1[row*192+64*j+lane] = acc;
  }
}

// recompute state1 rows for one (b,v), lane=f. 16 regs out + mask bits.
__device__ __forceinline__ void recompute_state1(
    int row, int b, int lane, int nn,
    const float* __restrict__ Yx1, const float* __restrict__ Hh1,
    const float* __restrict__ enc, const float* __restrict__ grub,
    const int* __restrict__ adj, float* s1, unsigned* maskbits)
{
  unsigned mb = 0;
  float gb0 = grub[lane], gb1 = grub[64+lane], gb2 = grub[128+lane];
  #pragma unroll
  for(int d=0; d<16; d++){
    int a = adj[row*16+d];
    bool m = (a==nn);
    if(m) mb |= (1u<<d);
    float inv = m ? 0.f : 1.f;
    int arow = (b<<11)+a;
    float x0 = inv*Yx1[arow*192+lane]     + gb0;
    float x1 = inv*Yx1[arow*192+64+lane]  + gb1;
    float x2 = inv*Yx1[arow*192+128+lane] + gb2;
    float h0 = inv*Hh1[arow*192+lane];
    float h1 = inv*Hh1[arow*192+64+lane];
    float h2 = inv*Hh1[arow*192+128+lane];
    float ini = inv*enc[arow*64+lane];
    float z = sigm(x0+h0);
    float r = sigm(x1+h1);
    float c = tanhf(x2 + r*h2);
    s1[d] = z*ini + (1.f-z)*c;
  }
  *maskbits = mb;
}

// ---------------- K3: layer-2 GAT agg + Yx2 ----------------
__global__ void k_agg2(const float* __restrict__ enc, const float* __restrict__ Yx1,
                       const float* __restrict__ Hh1,
                       const float* __restrict__ gatW, const float* __restrict__ gatb,
                       const float* __restrict__ gata,
                       const float* __restrict__ gruWx, const float* __restrict__ grub,
                       const int* __restrict__ adj, const int* __restrict__ num_nodes,
                       float* __restrict__ Yx2)
{
  __shared__ float S[4][16*65];
  __shared__ float AE[4][64];
  int wid = threadIdx.x>>6, lane = threadIdx.x&63;
  int row = blockIdx.x*4+wid; int b = row>>11;
  int nn = num_nodes[b];
  float s1[16]; unsigned mb;
  recompute_state1(row,b,lane,nn,Yx1,Hh1,enc,grub,adj,s1,&mb);
  #pragma unroll
  for(int d=0;d<16;d++) S[wid][d*65+lane] = s1[d];
  __syncthreads();
  float h2row[16]; float sc[16];
  float gbl = gatb[lane]; float gal = gata[lane];
  for(int d=0;d<16;d++){
    float acc = gbl;
    for(int k=0;k<64;k++) acc += S[wid][d*65+k]*gatW[k*64+lane];
    float h = tanhf(acc);
    h2row[d] = h;
    sc[d] = wsum64(h*gal) - (((mb>>d)&1) ? BIGC : 0.f);
  }
  float mx = sc[0];
  for(int d=1;d<16;d++) mx = fmaxf(mx,sc[d]);
  float den=0.f;
  for(int d=0;d<16;d++){ sc[d]=expf(sc[d]-mx); den+=sc[d]; }
  float invd = 1.f/den;
  float agg=0.f;
  for(int d=0;d<16;d++) agg += sc[d]*invd*h2row[d];
  AE[wid][lane] = agg + enc[row*64+lane];
  __syncthreads();
  for(int j=0;j<3;j++){
    float acc=0.f;
    for(int k=0;k<64;k++) acc += AE[wid][k]*gruWx[k*192+64*j+lane];
    Yx2[row*192+64*j+lane] = acc;
  }
}

// ---------------- K4: GRU2 + decoder node_weights + dual_vars ----------------
__global__ void k_final(const float* __restrict__ enc, const float* __restrict__ Yx1,
                        const float* __restrict__ Hh1, const float* __restrict__ Yx2,
                        const float* __restrict__ gruWh, const float* __restrict__ grub,
                        const float* __restrict__ dW1, const float* __restrict__ db1,
                        const float* __restrict__ dW2, const float* __restrict__ db2,
                        const float* __restrict__ uW1, const float* __restrict__ ub1,
                        const float* __restrict__ uW2, const float* __restrict__ ub2,
                        const int* __restrict__ adj, const int* __restrict__ num_nodes,
                        float* __restrict__ nw, float* __restrict__ dual_vars)
{
  __shared__ float S[4][16*65 + 64];
  int wid=threadIdx.x>>6, lane=threadIdx.x&63;
  int row = blockIdx.x*4+wid; int b=row>>11;
  int nn = num_nodes[b];
  float s1[16]; unsigned mb;
  recompute_state1(row,b,lane,nn,Yx1,Hh1,enc,grub,adj,s1,&mb);
  #pragma unroll
  for(int d=0;d<16;d++) S[wid][d*65+lane]=s1[d];
  __syncthreads();
  // hm2 = state1 @ gru_Wh, k-outer so Wh is read once
  float hm0[16], hm1[16], hm2_[16];
  #pragma unroll
  for(int d=0;d<16;d++){hm0[d]=0.f;hm1[d]=0.f;hm2_[d]=0.f;}
  for(int k=0;k<64;k++){
    float w0=gruWh[k*192+lane], w1=gruWh[k*192+64+lane], w2=gruWh[k*192+128+lane];
    #pragma unroll
    for(int d=0;d<16;d++){
      float s = S[wid][d*65+k];
      hm0[d] += s*w0; hm1[d] += s*w1; hm2_[d] += s*w2;
    }
  }
  float gb0=grub[lane], gb1=grub[64+lane], gb2=grub[128+lane];
  float s2[16]; float nsf=0.f;
  #pragma unroll
  for(int d=0;d<16;d++){
    int a = adj[row*16+d];
    float inv = ((mb>>d)&1) ? 0.f : 1.f;
    int arow=(b<<11)+a;
    float x0 = inv*Yx2[arow*192+lane]     + gb0;
    float x1 = inv*Yx2[arow*192+64+lane]  + gb1;
    float x2 = inv*Yx2[arow*192+128+lane] + gb2;
    float z = sigm(x0+hm0[d]);
    float r = sigm(x1+hm1[d]);
    float c = tanhf(x2 + r*hm2_[d]);
    float s_ = z*s1[d] + (1.f-z)*c;
    s2[d]=s_; nsf += s_;
  }
  __syncthreads();
  #pragma unroll
  for(int d=0;d<16;d++) S[wid][d*65+lane]=s2[d];
  S[wid][1040+lane]=nsf;
  __syncthreads();
  // decoder: element (d,j): d=lane&15, j = (lane>>4)*8 .. +7
  int dd = lane & 15, q = lane>>4;
  float tacc[8];
  #pragma unroll
  for(int j=0;j<8;j++) tacc[j]=0.f;
  for(int k=0;k<64;k++){
    float s = S[wid][dd*65+k];
    #pragma unroll
    for(int j=0;j<8;j++) tacc[j] += s*dW1[k*32 + q*8 + j];
  }
  float p = 0.f;
  #pragma unroll
  for(int j=0;j<8;j++){
    float t = tanhf(tacc[j] + db1[q*8+j]);
    p += t*dW2[q*8+j];
  }
  p += __shfl_xor(p,16,64);
  p += __shfl_xor(p,32,64);
  if(lane<16) nw[row*16+lane] = p + db2[0];
  // dual head on node_states
  float pu = 0.f;
  if(lane<32){
    float acc=0.f;
    for(int k=0;k<64;k++) acc += S[wid][1040+k]*uW1[k*32+lane];
    float t = tanhf(acc + ub1[lane]);
    pu = t*uW2[lane];
  }
  pu = wsum64(pu);
  if(lane==0) dual_vars[row] = pu + ub2[0];
}

// ---------------- K5: incoming gather + softmax(in) ----------------
__global__ void k_attn_in(const float* __restrict__ nw, const int* __restrict__ in_idx,
                          const int* __restrict__ inv_adj, const int* __restrict__ num_nodes,
                          float* __restrict__ attn_in)
{
  int gid = blockIdx.x*256+threadIdx.x;   // b*V+v
  int b = gid>>11;
  int nn = num_nodes[b];
  const float* nwb = nw + b*32768;
  float sc[16];
  int base = gid*16;
  #pragma unroll
  for(int d=0;d<16;d++){
    int ii = in_idx[base+d];
    float w = nwb[ii];
    bool im = (inv_adj[base+d]==nn);
    sc[d] = w - (im ? BIGC : 0.f);
  }
  float mx=sc[0];
  #pragma unroll
  for(int d=1;d<16;d++) mx=fmaxf(mx,sc[d]);
  float den=0.f;
  #pragma unroll
  for(int d=0;d<16;d++){sc[d]=expf(sc[d]-mx); den+=sc[d];}
  float inv=1.f/den;
  #pragma unroll
  for(int d=0;d<16;d++) attn_in[base+d] = sc[d]*inv;
}

// ---------------- K6: rev gather + softmax -> normalized ----------------
__global__ void k_norm(const float* __restrict__ attn_in, const int* __restrict__ rev_idx,
                       const int* __restrict__ adj, const int* __restrict__ num_nodes,
                       float* __restrict__ normalized)
{
  int gid = blockIdx.x*256+threadIdx.x;
  int b=gid>>11; int nn=num_nodes[b];
  const float* ab = attn_in + b*32768;
  int base=gid*16;
  float sc[16];
  #pragma unroll
  for(int d=0;d<16;d++){
    float g = ab[rev_idx[base+d]];
    bool m = (adj[base+d]==nn);
    sc[d] = g - (m?BIGC:0.f);
  }
  float mx=sc[0];
  #pragma unroll
  for(int d=1;d<16;d++) mx=fmaxf(mx,sc[d]);
  float den=0.f;
  #pragma unroll
  for(int d=0;d<16;d++){sc[d]=expf(sc[d]-mx); den+=sc[d];}
  float inv=1.f/den;
  #pragma unroll
  for(int d=0;d<16;d++) normalized[base+d]=sc[d]*inv;
}

// ---------------- K7: 10 MCF iterations + flow_cost, one block per b ----------------
__global__ void k_mcf(const float* __restrict__ normalized, const float* __restrict__ demands,
                      const int* __restrict__ in_idx, const int* __restrict__ inv_adj,
                      const int* __restrict__ num_nodes,
                      float* __restrict__ fA, float* __restrict__ fB, float* __restrict__ out)
{
  int b = blockIdx.x; int tid = threadIdx.x;  // 1024 threads
  int nn = num_nodes[b];
  const float* normb = normalized + b*32768;
  const int* inb  = in_idx + b*32768;
  const int* invb = inv_adj + b*32768;
  float* A = fA + b*32768; float* Bf = fB + b*32768;
  float sup[2];
  for(int s=0;s<2;s++){
    int vi = tid + s*1024;
    float dm = demands[b*2048+vi];
    sup[s] = fmaxf(-dm, 0.f);
    for(int d=0;d<16;d++) A[vi*16+d] = normb[vi*16+d]*sup[s];
  }
  __syncthreads();
  float* cur = A; float* nxt = Bf;
  for(int it=0; it<10; ++it){
    for(int s=0;s<2;s++){
      int vi = tid + s*1024;
      float infl = 0.f;
      #pragma unroll
      for(int d=0;d<16;d++){
        float w = cur[inb[vi*16+d]];
        infl += (invb[vi*16+d]==nn) ? 0.f : w;
      }
      float tot = infl + sup[s];
      #pragma unroll
      for(int d=0;d<16;d++) nxt[vi*16+d] = normb[vi*16+d]*tot;
    }
    __syncthreads();
    float* t = cur; cur = nxt; nxt = t;
  }
  float fc = 0.f;
  for(int s=0;s<2;s++){
    int vi = tid+s*1024;
    for(int d=0;d<16;d++){ float f = cur[vi*16+d]; fc += f*f; }
  }
  fc = wsum64(fc);
  __shared__ float red[16];
  int wid = tid>>6, lane = tid&63;
  if(lane==0) red[wid]=fc;
  __syncthreads();
  if(tid==0){
    float s=0.f;
    for(int i=0;i<16;i++) s+=red[i];
    atomicAdd(out+b, s);
  }
}

// ---------------- K8: dual iterations + dual_cost contribution ----------------
__global__ void k_dual(const float* __restrict__ dual_vars, const float* __restrict__ demands,
                       const int* __restrict__ adj, const int* __restrict__ num_nodes,
                       float* __restrict__ out)
{
  int gid = blockIdx.x*256+threadIdx.x;
  int b = gid>>11;
  int nn = num_nodes[b];
  float dv = dual_vars[gid];
  float contrib = dv * demands[gid];      // + dual_demand part
  #pragma unroll
  for(int d=0;d<16;d++){
    int a = adj[gid*16+d];
    bool m = (a==nn);
    float dvn = dual_vars[(b<<11)+a];
    float dd = m ? (-dv) : dvn;           // (1-m)*dvn - m*dv
    float valid = m ? 0.f : 1.f;
    float f=0.f, acc=0.f;
    #pragma unroll
    for(int it=0; it<10; ++it){
      float grad = 2.f*f + dd;
      acc = 0.9f*acc + 0.01f*grad;
      f = fmaxf(f-acc, 0.f)*valid;
    }
    contrib -= (f*f + dd*f);              // -X part
  }
  float s = wsum64(contrib);
  __shared__ float red[4];
  int wid = threadIdx.x>>6, lane = threadIdx.x&63;
  if(lane==0) red[wid]=s;
  __syncthreads();
  if(threadIdx.x==0) atomicAdd(out+b, red[0]+red[1]+red[2]+red[3]);
}

extern "C" void kernel_launch(void* const* d_in, const int* in_sizes, int n_in,
                              void* d_out, int out_size, void* d_ws, size_t ws_size,
                              hipStream_t stream)
{
  const float* feat = (const float*)d_in[0];
  const float* dem  = (const float*)d_in[1];
  const float* emb  = (const float*)d_in[2];
  const float* encW = (const float*)d_in[3];
  const float* encb = (const float*)d_in[4];
  const float* gatW = (const float*)d_in[5];
  const float* gatb = (const float*)d_in[6];
  const float* gata = (const float*)d_in[7];
  const float* gruWx= (const float*)d_in[8];
  const float* gruWh= (const float*)d_in[9];
  const float* grub = (const float*)d_in[10];
  const float* dW1  = (const float*)d_in[11];
  const float* db1  = (const float*)d_in[12];
  const float* dW2  = (const float*)d_in[13];
  const float* db2  = (const float*)d_in[14];
  const float* uW1  = (const float*)d_in[15];
  const float* ub1  = (const float*)d_in[16];
  const float* uW2  = (const float*)d_in[17];
  const float* ub2  = (const float*)d_in[18];
  const int* adj    = (const int*)d_in[19];
  const int* invadj = (const int*)d_in[20];
  const int* inidx  = (const int*)d_in[21];
  const int* revidx = (const int*)d_in[22];
  const int* nnodes = (const int*)d_in[23];
  float* out = (float*)d_out;

  float* ws = (float*)d_ws;
  size_t off=0;
  float* enc = ws+off; off += (size_t)8*2048*64;
  float* He  = ws+off; off += (size_t)8*2048*64;
  float* sHe = ws+off; off += (size_t)8*2048;
  float* Hh1 = ws+off; off += (size_t)8*2048*192;
  float* Yx1 = ws+off; off += (size_t)8*2048*192;
  float* Yx2 = ws+off; off += (size_t)8*2048*192;
  float* nwb = ws+off; off += (size_t)8*2048*16;
  float* attn= ws+off; off += (size_t)8*2048*16;
  float* nrm = ws+off; off += (size_t)8*2048*16;
  float* dv  = ws+off; off += (size_t)8*2048;
  float* fA  = ws+off; off += (size_t)8*2048*16;
  float* fB  = ws+off; off += (size_t)8*2048*16;
  (void)ws_size; (void)in_sizes; (void)n_in; (void)out_size;

  k_zero<<<1,64,0,stream>>>(out);
  k_enc<<<4096,256,0,stream>>>(feat,emb,encW,encb,gatW,gatb,gata,gruWh, enc,He,sHe,Hh1);
  k_agg1<<<4096,256,0,stream>>>(enc,He,sHe,gatb,gata,gruWx,adj,nnodes, Yx1);
  k_agg2<<<4096,256,0,stream>>>(enc,Yx1,Hh1,gatW,gatb,gata,gruWx,grub,adj,nnodes, Yx2);
  k_final<<<4096,256,0,stream>>>(enc,Yx1,Hh1,Yx2,gruWh,grub,dW1,db1,dW2,db2,uW1,ub1,uW2,ub2,adj,nnodes, nwb,dv);
  k_attn_in<<<64,256,0,stream>>>(nwb,inidx,invadj,nnodes, attn);
  k_norm<<<64,256,0,stream>>>(attn,revidx,adj,nnodes, nrm);
  k_mcf<<<8,1024,0,stream>>>(nrm,dem,inidx,invadj,nnodes, fA,fB,out);
  k_dual<<<64,256,0,stream>>>(dv,dem,adj,nnodes, out);
}

// Round 2
// 781.783 us; speedup vs baseline: 1.4378x; 1.4378x over previous
//
#include <hip/hip_runtime.h>
#include <math.h>

#define VV 2048
#define BIGC 1e9f

__device__ __forceinline__ float wsum64(float v){
  v += __shfl_xor(v, 1, 64);
  v += __shfl_xor(v, 2, 64);
  v += __shfl_xor(v, 4, 64);
  v += __shfl_xor(v, 8, 64);
  v += __shfl_xor(v, 16, 64);
  v += __shfl_xor(v, 32, 64);
  return v;
}
__device__ __forceinline__ float sigm(float x){ return 1.f/(1.f+expf(-x)); }

// ---------------- K_init: zero out + masked-edge constants ----------------
// C layout: [0:64) s1m | [64:128) h2m | [128] sh2m | [192:384) hm2m | [384:448) s2m | [448] nwm
__global__ void k_init(const float* __restrict__ gatW, const float* __restrict__ gatb,
                       const float* __restrict__ gata, const float* __restrict__ gruWh,
                       const float* __restrict__ grub,
                       const float* __restrict__ dW1, const float* __restrict__ db1,
                       const float* __restrict__ dW2, const float* __restrict__ db2,
                       float* __restrict__ out, float* __restrict__ C)
{
  int lane = threadIdx.x;   // 64 threads
  if(lane < 8) out[lane] = 0.f;
  float gb0 = grub[lane], gb1 = grub[64+lane], gb2 = grub[128+lane];
  float z1 = sigm(gb0);
  float s1m = (1.f - z1)*tanhf(gb2);
  C[lane] = s1m;
  float acc = gatb[lane];
  for(int k=0;k<64;k++) acc += __shfl(s1m,k,64)*gatW[k*64+lane];
  float h2m = tanhf(acc);
  C[64+lane] = h2m;
  float s = wsum64(h2m*gata[lane]);
  if(lane==0) C[128] = s;
  float hm[3];
  for(int j=0;j<3;j++){
    float a2 = 0.f;
    for(int k=0;k<64;k++) a2 += __shfl(s1m,k,64)*gruWh[k*192+64*j+lane];
    C[192+64*j+lane] = a2; hm[j] = a2;
  }
  float z2 = sigm(gb0 + hm[0]);
  float r2 = sigm(gb1 + hm[1]);
  float c2 = tanhf(gb2 + r2*hm[2]);
  float s2m = z2*s1m + (1.f-z2)*c2;
  C[384+lane] = s2m;
  // nwm = decoder(s2m)
  int h = lane & 31;
  float a3 = 0.f;
  for(int k=0;k<64;k++) a3 += __shfl(s2m,k,64)*dW1[k*32+h];
  float t = tanhf(a3 + db1[h]);
  float p = (lane < 32) ? t*dW2[h] : 0.f;
  p = wsum64(p);
  if(lane==0) C[448] = p + db2[0];
}

// ---------------- K_enc: per-node encoder + layer-1 precomputes ----------------
__global__ void k_enc(const float* __restrict__ feat, const float* __restrict__ emb,
                      const float* __restrict__ encW, const float* __restrict__ encb,
                      const float* __restrict__ gatW, const float* __restrict__ gatb,
                      const float* __restrict__ gata, const float* __restrict__ gruWh,
                      float* __restrict__ enc, float* __restrict__ HH,
                      float* __restrict__ sHH, float* __restrict__ Hh)
{
  __shared__ float L[4][112];
  int wid = threadIdx.x >> 6, lane = threadIdx.x & 63;
  int row = blockIdx.x*4 + wid;        // b*V + u
  int u = row & (VV-1);
  float ev = (lane < 32) ? emb[u*32 + lane] : 0.f;
  float ss = wsum64(ev*ev);
  float nrm = sqrtf(ss);
  float scale = (nrm > 1.f) ? 1.f/nrm : 1.f;
  if(lane < 32) L[wid][lane] = ev*scale;
  else if(lane < 48) L[wid][lane] = feat[row*16 + (lane-32)];
  __syncthreads();
  float e = encb[lane];
  #pragma unroll
  for(int k=0;k<48;k++) e += L[wid][k]*encW[k*64+lane];
  enc[row*64+lane] = e;
  L[wid][48+lane] = e;
  __syncthreads();
  float hacc = gatb[lane];
  for(int k=0;k<64;k++) hacc += L[wid][48+k]*gatW[k*64+lane];
  float h = tanhf(hacc);
  HH[row*64+lane] = h;
  float s = wsum64(h*gata[lane]);
  if(lane==0) sHH[row] = s;
  for(int j=0;j<3;j++){
    float acc = 0.f;
    for(int k=0;k<64;k++) acc += L[wid][48+k]*gruWh[k*192 + 64*j + lane];
    Hh[row*192 + 64*j + lane] = acc;
  }
}

// ---------------- K_agg1: layer-1 GAT agg + Yx1 = (agg1+enc)@Wx ----------------
__global__ void k_agg1(const float* __restrict__ enc, const float* __restrict__ HH,
                       const float* __restrict__ sHH,
                       const float* __restrict__ gatb, const float* __restrict__ gata,
                       const float* __restrict__ gruWx,
                       const int* __restrict__ adj, const int* __restrict__ num_nodes,
                       float* __restrict__ Yx)
{
  __shared__ float L[4][64];
  int wid = threadIdx.x>>6, lane = threadIdx.x & 63;
  int row = blockIdx.x*4 + wid;
  int b = row >> 11;
  int nn = num_nodes[b];
  float tb = tanhf(gatb[lane]);           // h row for masked (state=0)
  float cs = wsum64(tb*gata[lane]);
  float hrow[16]; float sc[16];
  #pragma unroll
  for(int d=0; d<16; d++){
    int a = adj[row*16+d];
    bool m = (a==nn);
    int arow = (b<<11) + a;
    hrow[d] = m ? tb : HH[arow*64+lane];
    sc[d]   = m ? (cs - BIGC) : sHH[arow];
  }
  float mx = sc[0];
  #pragma unroll
  for(int d=1;d<16;d++) mx = fmaxf(mx, sc[d]);
  float den = 0.f;
  #pragma unroll
  for(int d=0;d<16;d++){ sc[d] = expf(sc[d]-mx); den += sc[d]; }
  float invd = 1.f/den;
  float agg = 0.f;
  #pragma unroll
  for(int d=0;d<16;d++) agg += sc[d]*invd*hrow[d];
  L[wid][lane] = agg + enc[row*64+lane];
  __syncthreads();
  for(int j=0;j<3;j++){
    float acc = 0.f;
    for(int k=0;k<64;k++) acc += L[wid][k]*gruWx[k*192+64*j+lane];
    Yx[row*192+64*j+lane] = acc;
  }
}

// ---------------- K_node2: per-node GRU1 -> S1, H2, sH2, Hh2 ----------------
// Aliases: writes HH (over H1), Hh (over Hh1) AFTER reading own row.
__global__ void k_node2(const float* __restrict__ enc, const float* __restrict__ Yx,
                        float* __restrict__ Hh, const float* __restrict__ grub,
                        const float* __restrict__ gatW, const float* __restrict__ gatb,
                        const float* __restrict__ gata, const float* __restrict__ gruWh,
                        float* __restrict__ S1, float* __restrict__ HH,
                        float* __restrict__ sHH)
{
  __shared__ float L[4][64];
  int wid = threadIdx.x>>6, lane = threadIdx.x&63;
  int row = blockIdx.x*4+wid;
  float yx0 = Yx[row*192+lane], yx1 = Yx[row*192+64+lane], yx2 = Yx[row*192+128+lane];
  float hh0 = Hh[row*192+lane], hh1 = Hh[row*192+64+lane], hh2 = Hh[row*192+128+lane];
  float e = enc[row*64+lane];
  float gb0 = grub[lane], gb1 = grub[64+lane], gb2 = grub[128+lane];
  float z = sigm(yx0+gb0+hh0);
  float r = sigm(yx1+gb1+hh1);
  float c = tanhf(yx2+gb2+r*hh2);
  float s1 = z*e + (1.f-z)*c;
  S1[row*64+lane] = s1;
  L[wid][lane] = s1;
  __syncthreads();
  float hacc = gatb[lane];
  for(int k=0;k<64;k++) hacc += L[wid][k]*gatW[k*64+lane];
  float h2 = tanhf(hacc);
  HH[row*64+lane] = h2;
  float s = wsum64(h2*gata[lane]);
  if(lane==0) sHH[row] = s;
  for(int j=0;j<3;j++){
    float acc = 0.f;
    for(int k=0;k<64;k++) acc += L[wid][k]*gruWh[k*192+64*j+lane];
    Hh[row*192+64*j+lane] = acc;     // Hh2 over Hh1 (own row already read)
  }
}

// ---------------- K_agg2: layer-2 GAT agg + Yx2 (gather-based) ----------------
__global__ void k_agg2(const float* __restrict__ enc, const float* __restrict__ HH,
                       const float* __restrict__ sHH, const float* __restrict__ C,
                       const float* __restrict__ gata, const float* __restrict__ gruWx,
                       const int* __restrict__ adj, const int* __restrict__ num_nodes,
                       float* __restrict__ Yx)
{
  __shared__ float L[4][64];
  int wid = threadIdx.x>>6, lane = threadIdx.x&63;
  int row = blockIdx.x*4+wid;
  int b = row>>11;
  int nn = num_nodes[b];
  float h2m = C[64+lane];
  float sh2m = C[128];
  float hrow[16]; float sc[16];
  #pragma unroll
  for(int d=0; d<16; d++){
    int a = adj[row*16+d];
    bool m = (a==nn);
    int arow = (b<<11)+a;
    hrow[d] = m ? h2m : HH[arow*64+lane];
    sc[d]   = m ? (sh2m - BIGC) : sHH[arow];
  }
  float mx = sc[0];
  #pragma unroll
  for(int d=1;d<16;d++) mx = fmaxf(mx,sc[d]);
  float den=0.f;
  #pragma unroll
  for(int d=0;d<16;d++){ sc[d]=expf(sc[d]-mx); den+=sc[d]; }
  float invd = 1.f/den;
  float agg=0.f;
  #pragma unroll
  for(int d=0;d<16;d++) agg += sc[d]*invd*hrow[d];
  L[wid][lane] = agg + enc[row*64+lane];
  __syncthreads();
  for(int j=0;j<3;j++){
    float acc=0.f;
    for(int k=0;k<64;k++) acc += L[wid][k]*gruWx[k*192+64*j+lane];
    Yx[row*192+64*j+lane] = acc;     // Yx2 over Yx1 (Yx1 dead)
  }
}

// ---------------- K_node3: per-node GRU2 -> S2, decoder -> nwn ----------------
__global__ void k_node3(const float* __restrict__ S1, const float* __restrict__ Yx,
                        const float* __restrict__ Hh, const float* __restrict__ grub,
                        const float* __restrict__ dW1, const float* __restrict__ db1,
                        const float* __restrict__ dW2, const float* __restrict__ db2,
                        float* __restrict__ S2, float* __restrict__ nwn)
{
  int wid = threadIdx.x>>6, lane = threadIdx.x&63;
  int row = blockIdx.x*4+wid;
  float yx0 = Yx[row*192+lane], yx1 = Yx[row*192+64+lane], yx2 = Yx[row*192+128+lane];
  float hh0 = Hh[row*192+lane], hh1 = Hh[row*192+64+lane], hh2 = Hh[row*192+128+lane];
  float s1 = S1[row*64+lane];
  float gb0 = grub[lane], gb1 = grub[64+lane], gb2 = grub[128+lane];
  float z = sigm(yx0+gb0+hh0);
  float r = sigm(yx1+gb1+hh1);
  float c = tanhf(yx2+gb2+r*hh2);
  float s2 = z*s1 + (1.f-z)*c;
  S2[row*64+lane] = s2;              // aliases enc (dead)
  int h = lane & 31;
  float a = 0.f;
  for(int k=0;k<64;k++) a += __shfl(s2,k,64)*dW1[k*32+h];
  float t = tanhf(a + db1[h]);
  float p = (lane<32) ? t*dW2[h] : 0.f;
  p = wsum64(p);
  if(lane==0) nwn[row] = p + db2[0];
}

// ---------------- K_tail: node_states gather + dual head + nw gather ----------------
__global__ void k_tail(const float* __restrict__ S2, const float* __restrict__ nwn,
                       const float* __restrict__ C,
                       const float* __restrict__ uW1, const float* __restrict__ ub1,
                       const float* __restrict__ uW2, const float* __restrict__ ub2,
                       const int* __restrict__ adj, const int* __restrict__ num_nodes,
                       float* __restrict__ nw, float* __restrict__ dv)
{
  int wid = threadIdx.x>>6, lane = threadIdx.x&63;
  int row = blockIdx.x*4+wid;
  int b = row>>11;
  int nn = num_nodes[b];
  float s2m = C[384+lane];
  float nwm = C[448];
  float ns = 0.f;
  #pragma unroll
  for(int d=0;d<16;d++){
    int a = adj[row*16+d];
    bool m = (a==nn);
    ns += m ? s2m : S2[((b<<11)+a)*64+lane];
  }
  // nw gather (scalar per edge)
  if(lane < 16){
    int a = adj[row*16+lane];
    bool m = (a==nn);
    nw[row*16+lane] = m ? nwm : nwn[(b<<11)+a];
  }
  // dual head
  int h = lane & 31;
  float acc = 0.f;
  for(int k=0;k<64;k++) acc += __shfl(ns,k,64)*uW1[k*32+h];
  float t = tanhf(acc + ub1[h]);
  float p = (lane<32) ? t*uW2[h] : 0.f;
  p = wsum64(p);
  if(lane==0) dv[row] = p + ub2[0];
}

// ---------------- K5: incoming gather + softmax(in) ----------------
__global__ void k_attn_in(const float* __restrict__ nw, const int* __restrict__ in_idx,
                          const int* __restrict__ inv_adj, const int* __restrict__ num_nodes,
                          float* __restrict__ attn_in)
{
  int gid = blockIdx.x*256+threadIdx.x;   // b*V+v
  int b = gid>>11;
  int nn = num_nodes[b];
  const float* nwb = nw + b*32768;
  float sc[16];
  int base = gid*16;
  #pragma unroll
  for(int d=0;d<16;d++){
    int ii = in_idx[base+d];
    float w = nwb[ii];
    bool im = (inv_adj[base+d]==nn);
    sc[d] = w - (im ? BIGC : 0.f);
  }
  float mx=sc[0];
  #pragma unroll
  for(int d=1;d<16;d++) mx=fmaxf(mx,sc[d]);
  float den=0.f;
  #pragma unroll
  for(int d=0;d<16;d++){sc[d]=expf(sc[d]-mx); den+=sc[d];}
  float inv=1.f/den;
  #pragma unroll
  for(int d=0;d<16;d++) attn_in[base+d] = sc[d]*inv;
}

// ---------------- K6: rev gather + softmax -> normalized ----------------
__global__ void k_norm(const float* __restrict__ attn_in, const int* __restrict__ rev_idx,
                       const int* __restrict__ adj, const int* __restrict__ num_nodes,
                       float* __restrict__ normalized)
{
  int gid = blockIdx.x*256+threadIdx.x;
  int b=gid>>11; int nn=num_nodes[b];
  const float* ab = attn_in + b*32768;
  int base=gid*16;
  float sc[16];
  #pragma unroll
  for(int d=0;d<16;d++){
    float g = ab[rev_idx[base+d]];
    bool m = (adj[base+d]==nn);
    sc[d] = g - (m?BIGC:0.f);
  }
  float mx=sc[0];
  #pragma unroll
  for(int d=1;d<16;d++) mx=fmaxf(mx,sc[d]);
  float den=0.f;
  #pragma unroll
  for(int d=0;d<16;d++){sc[d]=expf(sc[d]-mx); den+=sc[d];}
  float inv=1.f/den;
  #pragma unroll
  for(int d=0;d<16;d++) normalized[base+d]=sc[d]*inv;
}

// ---------------- K7: 10 MCF iterations + flow_cost, one block per b ----------------
__global__ void k_mcf(const float* __restrict__ normalized, const float* __restrict__ demands,
                      const int* __restrict__ in_idx, const int* __restrict__ inv_adj,
                      const int* __restrict__ num_nodes,
                      float* __restrict__ fA, float* __restrict__ fB, float* __restrict__ out)
{
  int b = blockIdx.x; int tid = threadIdx.x;  // 1024 threads
  int nn = num_nodes[b];
  const float* normb = normalized + b*32768;
  const int* inb  = in_idx + b*32768;
  const int* invb = inv_adj + b*32768;
  float* A = fA + b*32768; float* Bf = fB + b*32768;
  float sup[2];
  for(int s=0;s<2;s++){
    int vi = tid + s*1024;
    float dm = demands[b*2048+vi];
    sup[s] = fmaxf(-dm, 0.f);
    for(int d=0;d<16;d++) A[vi*16+d] = normb[vi*16+d]*sup[s];
  }
  __syncthreads();
  float* cur = A; float* nxt = Bf;
  for(int it=0; it<10; ++it){
    for(int s=0;s<2;s++){
      int vi = tid + s*1024;
      float infl = 0.f;
      #pragma unroll
      for(int d=0;d<16;d++){
        float w = cur[inb[vi*16+d]];
        infl += (invb[vi*16+d]==nn) ? 0.f : w;
      }
      float tot = infl + sup[s];
      #pragma unroll
      for(int d=0;d<16;d++) nxt[vi*16+d] = normb[vi*16+d]*tot;
    }
    __syncthreads();
    float* t = cur; cur = nxt; nxt = t;
  }
  float fc = 0.f;
  for(int s=0;s<2;s++){
    int vi = tid+s*1024;
    for(int d=0;d<16;d++){ float f = cur[vi*16+d]; fc += f*f; }
  }
  fc = wsum64(fc);
  __shared__ float red[16];
  int wid = tid>>6, lane = tid&63;
  if(lane==0) red[wid]=fc;
  __syncthreads();
  if(tid==0){
    float s=0.f;
    for(int i=0;i<16;i++) s+=red[i];
    atomicAdd(out+b, s);
  }
}

// ---------------- K8: dual iterations + dual_cost contribution ----------------
__global__ void k_dual(const float* __restrict__ dual_vars, const float* __restrict__ demands,
                       const int* __restrict__ adj, const int* __restrict__ num_nodes,
                       float* __restrict__ out)
{
  int gid = blockIdx.x*256+threadIdx.x;
  int b = gid>>11;
  int nn = num_nodes[b];
  float dvv = dual_vars[gid];
  float contrib = dvv * demands[gid];      // + dual_demand part
  #pragma unroll
  for(int d=0;d<16;d++){
    int a = adj[gid*16+d];
    bool m = (a==nn);
    float dvn = dual_vars[(b<<11)+a];
    float dd = m ? (-dvv) : dvn;           // (1-m)*dvn - m*dv
    float valid = m ? 0.f : 1.f;
    float f=0.f, acc=0.f;
    #pragma unroll
    for(int it=0; it<10; ++it){
      float grad = 2.f*f + dd;
      acc = 0.9f*acc + 0.01f*grad;
      f = fmaxf(f-acc, 0.f)*valid;
    }
    contrib -= (f*f + dd*f);              // -X part
  }
  float s = wsum64(contrib);
  __shared__ float red[4];
  int wid = threadIdx.x>>6, lane = threadIdx.x&63;
  if(lane==0) red[wid]=s;
  __syncthreads();
  if(threadIdx.x==0) atomicAdd(out+b, red[0]+red[1]+red[2]+red[3]);
}

extern "C" void kernel_launch(void* const* d_in, const int* in_sizes, int n_in,
                              void* d_out, int out_size, void* d_ws, size_t ws_size,
                              hipStream_t stream)
{
  const float* feat = (const float*)d_in[0];
  const float* dem  = (const float*)d_in[1];
  const float* emb  = (const float*)d_in[2];
  const float* encW = (const float*)d_in[3];
  const float* encb = (const float*)d_in[4];
  const float* gatW = (const float*)d_in[5];
  const float* gatb = (const float*)d_in[6];
  const float* gata = (const float*)d_in[7];
  const float* gruWx= (const float*)d_in[8];
  const float* gruWh= (const float*)d_in[9];
  const float* grub = (const float*)d_in[10];
  const float* dW1  = (const float*)d_in[11];
  const float* db1  = (const float*)d_in[12];
  const float* dW2  = (const float*)d_in[13];
  const float* db2  = (const float*)d_in[14];
  const float* uW1  = (const float*)d_in[15];
  const float* ub1  = (const float*)d_in[16];
  const float* uW2  = (const float*)d_in[17];
  const float* ub2  = (const float*)d_in[18];
  const int* adj    = (const int*)d_in[19];
  const int* invadj = (const int*)d_in[20];
  const int* inidx  = (const int*)d_in[21];
  const int* revidx = (const int*)d_in[22];
  const int* nnodes = (const int*)d_in[23];
  float* out = (float*)d_out;

  float* ws = (float*)d_ws;
  size_t off=0;
  float* enc = ws+off; off += (size_t)16384*64;     // later aliased as S2
  float* HH  = ws+off; off += (size_t)16384*64;     // H1 then H2
  float* sHH = ws+off; off += (size_t)16384;        // sH1 then sH2
  float* Hh  = ws+off; off += (size_t)16384*192;    // Hh1 then Hh2
  float* Yx  = ws+off; off += (size_t)16384*192;    // Yx1 then Yx2
  float* S1  = ws+off; off += (size_t)16384*64;
  float* nwn = ws+off; off += (size_t)16384;
  float* C   = ws+off; off += (size_t)512;
  float* nwb = ws+off; off += (size_t)16384*16;
  float* attn= ws+off; off += (size_t)16384*16;
  float* nrm = ws+off; off += (size_t)16384*16;
  float* dv  = ws+off; off += (size_t)16384;
  float* fA  = ws+off; off += (size_t)16384*16;
  float* fB  = ws+off; off += (size_t)16384*16;
  float* S2  = enc;   // alias: enc dead after k_agg2
  (void)ws_size; (void)in_sizes; (void)n_in; (void)out_size;

  k_init<<<1,64,0,stream>>>(gatW,gatb,gata,gruWh,grub,dW1,db1,dW2,db2, out,C);
  k_enc<<<4096,256,0,stream>>>(feat,emb,encW,encb,gatW,gatb,gata,gruWh, enc,HH,sHH,Hh);
  k_agg1<<<4096,256,0,stream>>>(enc,HH,sHH,gatb,gata,gruWx,adj,nnodes, Yx);
  k_node2<<<4096,256,0,stream>>>(enc,Yx,Hh,grub,gatW,gatb,gata,gruWh, S1,HH,sHH);
  k_agg2<<<4096,256,0,stream>>>(enc,HH,sHH,C,gata,gruWx,adj,nnodes, Yx);
  k_node3<<<4096,256,0,stream>>>(S1,Yx,Hh,grub,dW1,db1,dW2,db2, S2,nwn);
  k_tail<<<4096,256,0,stream>>>(S2,nwn,C,uW1,ub1,uW2,ub2,adj,nnodes, nwb,dv);
  k_attn_in<<<64,256,0,stream>>>(nwb,inidx,invadj,nnodes, attn);
  k_norm<<<64,256,0,stream>>>(attn,revidx,adj,nnodes, nrm);
  k_mcf<<<8,1024,0,stream>>>(nrm,dem,inidx,invadj,nnodes, fA,fB,out);
  k_dual<<<64,256,0,stream>>>(dv,dem,adj,nnodes, out);
}

// Round 3
// 574.921 us; speedup vs baseline: 1.9551x; 1.3598x over previous
//
#include <hip/hip_runtime.h>
#include <math.h>

#define VV 2048
#define BIGC 1e9f

__device__ __forceinline__ float wsum64(float v){
  v += __shfl_xor(v, 1, 64);
  v += __shfl_xor(v, 2, 64);
  v += __shfl_xor(v, 4, 64);
  v += __shfl_xor(v, 8, 64);
  v += __shfl_xor(v, 16, 64);
  v += __shfl_xor(v, 32, 64);
  return v;
}
__device__ __forceinline__ float sigm(float x){ return 1.f/(1.f+expf(-x)); }

// ---------------- K_init: zero out + masked-edge constants ----------------
// C layout: [0:64) s1m | [64:128) h2m | [128] sh2m | [384:448) s2m | [448] nwm
__global__ void k_init(const float* __restrict__ gatW, const float* __restrict__ gatb,
                       const float* __restrict__ gata, const float* __restrict__ gruWh,
                       const float* __restrict__ grub,
                       const float* __restrict__ dW1, const float* __restrict__ db1,
                       const float* __restrict__ dW2, const float* __restrict__ db2,
                       float* __restrict__ out, float* __restrict__ C)
{
  int lane = threadIdx.x;   // 64 threads
  if(lane < 8) out[lane] = 0.f;
  float gb0 = grub[lane], gb1 = grub[64+lane], gb2 = grub[128+lane];
  float z1 = sigm(gb0);
  float s1m = (1.f - z1)*tanhf(gb2);
  C[lane] = s1m;
  float acc = gatb[lane];
  for(int k=0;k<64;k++) acc += __shfl(s1m,k,64)*gatW[k*64+lane];
  float h2m = tanhf(acc);
  C[64+lane] = h2m;
  float s = wsum64(h2m*gata[lane]);
  if(lane==0) C[128] = s;
  float hm[3];
  for(int j=0;j<3;j++){
    float a2 = 0.f;
    for(int k=0;k<64;k++) a2 += __shfl(s1m,k,64)*gruWh[k*192+64*j+lane];
    hm[j] = a2;
  }
  float z2 = sigm(gb0 + hm[0]);
  float r2 = sigm(gb1 + hm[1]);
  float c2 = tanhf(gb2 + r2*hm[2]);
  float s2m = z2*s1m + (1.f-z2)*c2;
  C[384+lane] = s2m;
  int h = lane & 31;
  float a3 = 0.f;
  for(int k=0;k<64;k++) a3 += __shfl(s2m,k,64)*dW1[k*32+h];
  float t = tanhf(a3 + db1[h]);
  float p = (lane < 32) ? t*dW2[h] : 0.f;
  p = wsum64(p);
  if(lane==0) C[448] = p + db2[0];
}

// ---------------- K_enc: per-node encoder + H1/sH1. 4 rows/wave ----------------
__global__ void k_enc(const float* __restrict__ feat, const float* __restrict__ emb,
                      const float* __restrict__ encW, const float* __restrict__ encb,
                      const float* __restrict__ gatW, const float* __restrict__ gatb,
                      const float* __restrict__ gata,
                      float* __restrict__ enc, float* __restrict__ HH,
                      float* __restrict__ sHH)
{
  __shared__ float IN[4][192];
  __shared__ float E[4][256];
  int wid = threadIdx.x >> 6, lane = threadIdx.x & 63;
  int base = (blockIdx.x*4 + wid)*4;
  #pragma unroll
  for(int r=0;r<4;r++){
    int row = base+r; int u = row & (VV-1);
    float ev = (lane < 32) ? emb[u*32 + lane] : 0.f;
    float ss = wsum64(ev*ev);
    float scale = (ss > 1.f) ? 1.f/sqrtf(ss) : 1.f;
    if(lane < 32) IN[wid][r*48+lane] = ev*scale;
    else if(lane < 48) IN[wid][r*48+lane] = feat[row*16 + (lane-32)];
  }
  float acc[4];
  #pragma unroll
  for(int r=0;r<4;r++) acc[r] = encb[lane];
  for(int k=0;k<48;k++){
    float wv = encW[k*64+lane];
    #pragma unroll
    for(int r=0;r<4;r++) acc[r] += IN[wid][r*48+k]*wv;
  }
  #pragma unroll
  for(int r=0;r<4;r++){
    enc[(base+r)*64+lane] = acc[r];
    E[wid][r*64+lane] = acc[r];
  }
  float h[4];
  #pragma unroll
  for(int r=0;r<4;r++) h[r] = gatb[lane];
  for(int k=0;k<64;k++){
    float wv = gatW[k*64+lane];
    #pragma unroll
    for(int r=0;r<4;r++) h[r] += E[wid][r*64+k]*wv;
  }
  float gal = gata[lane];
  #pragma unroll
  for(int r=0;r<4;r++){
    float hv = tanhf(h[r]);
    HH[(base+r)*64+lane] = hv;
    float s = wsum64(hv*gal);
    if(lane==0) sHH[base+r] = s;
  }
}

// ---------------- K_layer1: GAT1 agg + Yx1 + Hh1 + GRU1 + H2/sH2. 4 rows/wave ----------------
__global__ void k_layer1(const float* __restrict__ enc, const float* __restrict__ HH1,
                         const float* __restrict__ sHH1,
                         const float* __restrict__ gatW, const float* __restrict__ gatb,
                         const float* __restrict__ gata,
                         const float* __restrict__ gruWx, const float* __restrict__ gruWh,
                         const float* __restrict__ grub,
                         const int* __restrict__ adj, const int* __restrict__ num_nodes,
                         float* __restrict__ S1, float* __restrict__ HH2,
                         float* __restrict__ sHH2)
{
  __shared__ float LX[4][256];
  __shared__ float LE[4][256];
  __shared__ float LS[4][256];
  int wid = threadIdx.x>>6, lane = threadIdx.x & 63;
  int base = (blockIdx.x*4 + wid)*4;
  int b = base >> 11;
  int nn = num_nodes[b];
  float tb = tanhf(gatb[lane]);           // h row for masked (state=0)
  float gal = gata[lane];
  float cs = wsum64(tb*gal);
  float e[4];
  #pragma unroll
  for(int r=0;r<4;r++){
    int row = base+r;
    float hrow[16], sc[16];
    #pragma unroll
    for(int d=0; d<16; d++){
      int a = adj[row*16+d];
      bool m = (a==nn);
      int arow = (b<<11) + a;
      hrow[d] = m ? tb : HH1[arow*64+lane];
      sc[d]   = m ? (cs - BIGC) : sHH1[arow];
    }
    float mx = sc[0];
    #pragma unroll
    for(int d=1;d<16;d++) mx = fmaxf(mx, sc[d]);
    float den = 0.f;
    #pragma unroll
    for(int d=0;d<16;d++){ sc[d] = expf(sc[d]-mx); den += sc[d]; }
    float invd = 1.f/den;
    float agg = 0.f;
    #pragma unroll
    for(int d=0;d<16;d++) agg += sc[d]*invd*hrow[d];
    e[r] = enc[row*64+lane];
    float x = agg + e[r];
    LX[wid][r*64+lane] = x;
    LE[wid][r*64+lane] = e[r];
  }
  float ax[4][3], ah[4][3];
  #pragma unroll
  for(int r=0;r<4;r++)
    #pragma unroll
    for(int j=0;j<3;j++){ ax[r][j]=0.f; ah[r][j]=0.f; }
  for(int k=0;k<64;k++){
    float bx[4], be[4];
    #pragma unroll
    for(int r=0;r<4;r++){ bx[r]=LX[wid][r*64+k]; be[r]=LE[wid][r*64+k]; }
    #pragma unroll
    for(int j=0;j<3;j++){
      float wx = gruWx[k*192+64*j+lane];
      float wh = gruWh[k*192+64*j+lane];
      #pragma unroll
      for(int r=0;r<4;r++){ ax[r][j] += bx[r]*wx; ah[r][j] += be[r]*wh; }
    }
  }
  float gb0 = grub[lane], gb1 = grub[64+lane], gb2 = grub[128+lane];
  #pragma unroll
  for(int r=0;r<4;r++){
    float z = sigm(ax[r][0]+gb0+ah[r][0]);
    float rr = sigm(ax[r][1]+gb1+ah[r][1]);
    float c = tanhf(ax[r][2]+gb2+rr*ah[r][2]);
    float s1 = z*e[r] + (1.f-z)*c;
    S1[(base+r)*64+lane] = s1;
    LS[wid][r*64+lane] = s1;
  }
  float h[4];
  #pragma unroll
  for(int r=0;r<4;r++) h[r] = gatb[lane];
  for(int k=0;k<64;k++){
    float wv = gatW[k*64+lane];
    #pragma unroll
    for(int r=0;r<4;r++) h[r] += LS[wid][r*64+k]*wv;
  }
  #pragma unroll
  for(int r=0;r<4;r++){
    float hv = tanhf(h[r]);
    HH2[(base+r)*64+lane] = hv;
    float s = wsum64(hv*gal);
    if(lane==0) sHH2[base+r] = s;
  }
}

// ---------------- K_layer2: GAT2 agg + Yx2 + Hm2 + GRU2 + decoder. 4 rows/wave ----------------
__global__ void k_layer2(const float* __restrict__ enc, const float* __restrict__ HH2,
                         const float* __restrict__ sHH2, const float* __restrict__ C,
                         const float* __restrict__ gata,
                         const float* __restrict__ gruWx, const float* __restrict__ gruWh,
                         const float* __restrict__ grub,
                         const float* __restrict__ dW1, const float* __restrict__ db1,
                         const float* __restrict__ dW2, const float* __restrict__ db2,
                         const int* __restrict__ adj, const int* __restrict__ num_nodes,
                         const float* __restrict__ S1,
                         float* __restrict__ S2, float* __restrict__ nwn)
{
  __shared__ float LX[4][256];
  __shared__ float LS1[4][256];
  __shared__ float LS2[4][256];
  int wid = threadIdx.x>>6, lane = threadIdx.x & 63;
  int base = (blockIdx.x*4 + wid)*4;
  int b = base >> 11;
  int nn = num_nodes[b];
  float h2m = C[64+lane];
  float sh2m = C[128];
  float s1v[4];
  #pragma unroll
  for(int r=0;r<4;r++){
    int row = base+r;
    float hrow[16], sc[16];
    #pragma unroll
    for(int d=0; d<16; d++){
      int a = adj[row*16+d];
      bool m = (a==nn);
      int arow = (b<<11)+a;
      hrow[d] = m ? h2m : HH2[arow*64+lane];
      sc[d]   = m ? (sh2m - BIGC) : sHH2[arow];
    }
    float mx = sc[0];
    #pragma unroll
    for(int d=1;d<16;d++) mx = fmaxf(mx,sc[d]);
    float den=0.f;
    #pragma unroll
    for(int d=0;d<16;d++){ sc[d]=expf(sc[d]-mx); den+=sc[d]; }
    float invd = 1.f/den;
    float agg=0.f;
    #pragma unroll
    for(int d=0;d<16;d++) agg += sc[d]*invd*hrow[d];
    float x = agg + enc[row*64+lane];
    s1v[r] = S1[row*64+lane];
    LX[wid][r*64+lane] = x;
    LS1[wid][r*64+lane] = s1v[r];
  }
  float ax[4][3], am[4][3];
  #pragma unroll
  for(int r=0;r<4;r++)
    #pragma unroll
    for(int j=0;j<3;j++){ ax[r][j]=0.f; am[r][j]=0.f; }
  for(int k=0;k<64;k++){
    float bx[4], bs[4];
    #pragma unroll
    for(int r=0;r<4;r++){ bx[r]=LX[wid][r*64+k]; bs[r]=LS1[wid][r*64+k]; }
    #pragma unroll
    for(int j=0;j<3;j++){
      float wx = gruWx[k*192+64*j+lane];
      float wh = gruWh[k*192+64*j+lane];
      #pragma unroll
      for(int r=0;r<4;r++){ ax[r][j] += bx[r]*wx; am[r][j] += bs[r]*wh; }
    }
  }
  float gb0 = grub[lane], gb1 = grub[64+lane], gb2 = grub[128+lane];
  #pragma unroll
  for(int r=0;r<4;r++){
    float z = sigm(ax[r][0]+gb0+am[r][0]);
    float rr = sigm(ax[r][1]+gb1+am[r][1]);
    float c = tanhf(ax[r][2]+gb2+rr*am[r][2]);
    float s2 = z*s1v[r] + (1.f-z)*c;
    S2[(base+r)*64+lane] = s2;
    LS2[wid][r*64+lane] = s2;
  }
  // decoder
  int h = lane & 31;
  float accd[4];
  #pragma unroll
  for(int r=0;r<4;r++) accd[r]=0.f;
  for(int k=0;k<64;k++){
    float wv = dW1[k*32+h];
    #pragma unroll
    for(int r=0;r<4;r++) accd[r] += LS2[wid][r*64+k]*wv;
  }
  float b1 = db1[h], w2 = dW2[h], b2 = db2[0];
  #pragma unroll
  for(int r=0;r<4;r++){
    float t = tanhf(accd[r] + b1);
    float p = (lane<32) ? t*w2 : 0.f;
    p = wsum64(p);
    if(lane==0) nwn[base+r] = p + b2;
  }
}

// ---------------- K_tail: node_states gather + dual head + nw gather. 4 rows/wave ----------------
__global__ void k_tail(const float* __restrict__ S2, const float* __restrict__ nwn,
                       const float* __restrict__ C,
                       const float* __restrict__ uW1, const float* __restrict__ ub1,
                       const float* __restrict__ uW2, const float* __restrict__ ub2,
                       const int* __restrict__ adj, const int* __restrict__ num_nodes,
                       float* __restrict__ nw, float* __restrict__ dv)
{
  __shared__ float LN[4][256];
  int wid = threadIdx.x>>6, lane = threadIdx.x&63;
  int base = (blockIdx.x*4+wid)*4;
  int b = base>>11;
  int nn = num_nodes[b];
  float s2m = C[384+lane];
  float nwm = C[448];
  #pragma unroll
  for(int r=0;r<4;r++){
    int row = base+r;
    float ns = 0.f;
    #pragma unroll
    for(int d=0;d<16;d++){
      int a = adj[row*16+d];
      bool m = (a==nn);
      ns += m ? s2m : S2[((b<<11)+a)*64+lane];
    }
    LN[wid][r*64+lane] = ns;
    if(lane < 16){
      int a = adj[row*16+lane];
      bool m = (a==nn);
      nw[row*16+lane] = m ? nwm : nwn[(b<<11)+a];
    }
  }
  int h = lane & 31;
  float acc[4];
  #pragma unroll
  for(int r=0;r<4;r++) acc[r]=0.f;
  for(int k=0;k<64;k++){
    float wv = uW1[k*32+h];
    #pragma unroll
    for(int r=0;r<4;r++) acc[r] += LN[wid][r*64+k]*wv;
  }
  float b1 = ub1[h], w2 = uW2[h], b2 = ub2[0];
  #pragma unroll
  for(int r=0;r<4;r++){
    float t = tanhf(acc[r] + b1);
    float p = (lane<32) ? t*w2 : 0.f;
    p = wsum64(p);
    if(lane==0) dv[base+r] = p + b2;
  }
}

// ---------------- K5: incoming gather + softmax(in) ----------------
__global__ void k_attn_in(const float* __restrict__ nw, const int* __restrict__ in_idx,
                          const int* __restrict__ inv_adj, const int* __restrict__ num_nodes,
                          float* __restrict__ attn_in)
{
  int gid = blockIdx.x*256+threadIdx.x;   // b*V+v
  int b = gid>>11;
  int nn = num_nodes[b];
  const float* nwb = nw + b*32768;
  float sc[16];
  int base = gid*16;
  #pragma unroll
  for(int d=0;d<16;d++){
    int ii = in_idx[base+d];
    float w = nwb[ii];
    bool im = (inv_adj[base+d]==nn);
    sc[d] = w - (im ? BIGC : 0.f);
  }
  float mx=sc[0];
  #pragma unroll
  for(int d=1;d<16;d++) mx=fmaxf(mx,sc[d]);
  float den=0.f;
  #pragma unroll
  for(int d=0;d<16;d++){sc[d]=expf(sc[d]-mx); den+=sc[d];}
  float inv=1.f/den;
  #pragma unroll
  for(int d=0;d<16;d++) attn_in[base+d] = sc[d]*inv;
}

// ---------------- K6: rev gather + softmax -> normalized ----------------
__global__ void k_norm(const float* __restrict__ attn_in, const int* __restrict__ rev_idx,
                       const int* __restrict__ adj, const int* __restrict__ num_nodes,
                       float* __restrict__ normalized)
{
  int gid = blockIdx.x*256+threadIdx.x;
  int b=gid>>11; int nn=num_nodes[b];
  const float* ab = attn_in + b*32768;
  int base=gid*16;
  float sc[16];
  #pragma unroll
  for(int d=0;d<16;d++){
    float g = ab[rev_idx[base+d]];
    bool m = (adj[base+d]==nn);
    sc[d] = g - (m?BIGC:0.f);
  }
  float mx=sc[0];
  #pragma unroll
  for(int d=1;d<16;d++) mx=fmaxf(mx,sc[d]);
  float den=0.f;
  #pragma unroll
  for(int d=0;d<16;d++){sc[d]=expf(sc[d]-mx); den+=sc[d];}
  float inv=1.f/den;
  #pragma unroll
  for(int d=0;d<16;d++) normalized[base+d]=sc[d]*inv;
}

// ---------------- K7: MCF via per-node scalar iteration in LDS ----------------
// flow[v,:] = norm[v,:]*tot[v]; tot' = sup + sum_d w[v,d]*tot[src[v,d]]
__global__ void k_mcf(const float* __restrict__ normalized, const float* __restrict__ demands,
                      const int* __restrict__ in_idx, const int* __restrict__ inv_adj,
                      const int* __restrict__ num_nodes,
                      float* __restrict__ out)
{
  __shared__ float T[2][2048];
  int b = blockIdx.x; int tid = threadIdx.x;  // 1024 threads
  int nn = num_nodes[b];
  const float* nb = normalized + b*32768;
  const int* ib  = in_idx + b*32768;
  const int* vb  = inv_adj + b*32768;
  float sup[2], q[2];
  float w[2][16]; int src[2][16];
  #pragma unroll
  for(int s=0;s<2;s++){
    int vi = tid + s*1024;
    float dm = demands[b*2048+vi];
    sup[s] = fmaxf(-dm, 0.f);
    float qq = 0.f;
    #pragma unroll
    for(int d=0;d<16;d++){
      float nv = nb[vi*16+d];
      qq += nv*nv;
    }
    q[s] = qq;
    #pragma unroll
    for(int d=0;d<16;d++){
      int ii = ib[vi*16+d];
      bool im = (vb[vi*16+d]==nn);
      w[s][d] = im ? 0.f : nb[ii];
      src[s][d] = ii >> 4;
    }
    T[0][vi] = sup[s];
  }
  __syncthreads();
  int cur = 0;
  for(int it=0; it<10; ++it){
    float nt[2];
    #pragma unroll
    for(int s=0;s<2;s++){
      float acc = sup[s];
      #pragma unroll
      for(int d=0;d<16;d++) acc += w[s][d]*T[cur][src[s][d]];
      nt[s] = acc;
    }
    #pragma unroll
    for(int s=0;s<2;s++) T[cur^1][tid+s*1024] = nt[s];
    __syncthreads();
    cur ^= 1;
  }
  float fc = q[0]*T[cur][tid]*T[cur][tid] + q[1]*T[cur][tid+1024]*T[cur][tid+1024];
  fc = wsum64(fc);
  __shared__ float red[16];
  int wid = tid>>6, lane = tid&63;
  if(lane==0) red[wid]=fc;
  __syncthreads();
  if(tid==0){
    float s=0.f;
    for(int i=0;i<16;i++) s+=red[i];
    atomicAdd(out+b, s);
  }
}

// ---------------- K8: dual iterations + dual_cost contribution ----------------
__global__ void k_dual(const float* __restrict__ dual_vars, const float* __restrict__ demands,
                       const int* __restrict__ adj, const int* __restrict__ num_nodes,
                       float* __restrict__ out)
{
  int gid = blockIdx.x*256+threadIdx.x;
  int b = gid>>11;
  int nn = num_nodes[b];
  float dvv = dual_vars[gid];
  float contrib = dvv * demands[gid];      // + dual_demand part
  #pragma unroll
  for(int d=0;d<16;d++){
    int a = adj[gid*16+d];
    bool m = (a==nn);
    float dvn = dual_vars[(b<<11)+a];
    float dd = m ? (-dvv) : dvn;           // (1-m)*dvn - m*dv
    float valid = m ? 0.f : 1.f;
    float f=0.f, acc=0.f;
    #pragma unroll
    for(int it=0; it<10; ++it){
      float grad = 2.f*f + dd;
      acc = 0.9f*acc + 0.01f*grad;
      f = fmaxf(f-acc, 0.f)*valid;
    }
    contrib -= (f*f + dd*f);              // -X part
  }
  float s = wsum64(contrib);
  __shared__ float red[4];
  int wid = threadIdx.x>>6, lane = threadIdx.x&63;
  if(lane==0) red[wid]=s;
  __syncthreads();
  if(threadIdx.x==0) atomicAdd(out+b, red[0]+red[1]+red[2]+red[3]);
}

extern "C" void kernel_launch(void* const* d_in, const int* in_sizes, int n_in,
                              void* d_out, int out_size, void* d_ws, size_t ws_size,
                              hipStream_t stream)
{
  const float* feat = (const float*)d_in[0];
  const float* dem  = (const float*)d_in[1];
  const float* emb  = (const float*)d_in[2];
  const float* encW = (const float*)d_in[3];
  const float* encb = (const float*)d_in[4];
  const float* gatW = (const float*)d_in[5];
  const float* gatb = (const float*)d_in[6];
  const float* gata = (const float*)d_in[7];
  const float* gruWx= (const float*)d_in[8];
  const float* gruWh= (const float*)d_in[9];
  const float* grub = (const float*)d_in[10];
  const float* dW1  = (const float*)d_in[11];
  const float* db1  = (const float*)d_in[12];
  const float* dW2  = (const float*)d_in[13];
  const float* db2  = (const float*)d_in[14];
  const float* uW1  = (const float*)d_in[15];
  const float* ub1  = (const float*)d_in[16];
  const float* uW2  = (const float*)d_in[17];
  const float* ub2  = (const float*)d_in[18];
  const int* adj    = (const int*)d_in[19];
  const int* invadj = (const int*)d_in[20];
  const int* inidx  = (const int*)d_in[21];
  const int* revidx = (const int*)d_in[22];
  const int* nnodes = (const int*)d_in[23];
  float* out = (float*)d_out;

  float* ws = (float*)d_ws;
  size_t off=0;
  float* enc  = ws+off; off += (size_t)16384*64;
  float* HH1  = ws+off; off += (size_t)16384*64;
  float* sHH1 = ws+off; off += (size_t)16384;
  float* S1   = ws+off; off += (size_t)16384*64;
  float* HH2  = ws+off; off += (size_t)16384*64;
  float* sHH2 = ws+off; off += (size_t)16384;
  float* S2   = ws+off; off += (size_t)16384*64;
  float* nwn  = ws+off; off += (size_t)16384;
  float* C    = ws+off; off += (size_t)512;
  float* nwb  = ws+off; off += (size_t)16384*16;
  float* attn = ws+off; off += (size_t)16384*16;
  float* nrm  = ws+off; off += (size_t)16384*16;
  float* dv   = ws+off; off += (size_t)16384;
  (void)ws_size; (void)in_sizes; (void)n_in; (void)out_size;

  k_init<<<1,64,0,stream>>>(gatW,gatb,gata,gruWh,grub,dW1,db1,dW2,db2, out,C);
  k_enc<<<1024,256,0,stream>>>(feat,emb,encW,encb,gatW,gatb,gata, enc,HH1,sHH1);
  k_layer1<<<1024,256,0,stream>>>(enc,HH1,sHH1,gatW,gatb,gata,gruWx,gruWh,grub,adj,nnodes, S1,HH2,sHH2);
  k_layer2<<<1024,256,0,stream>>>(enc,HH2,sHH2,C,gata,gruWx,gruWh,grub,dW1,db1,dW2,db2,adj,nnodes,S1, S2,nwn);
  k_tail<<<1024,256,0,stream>>>(S2,nwn,C,uW1,ub1,uW2,ub2,adj,nnodes, nwb,dv);
  k_attn_in<<<64,256,0,stream>>>(nwb,inidx,invadj,nnodes, attn);
  k_norm<<<64,256,0,stream>>>(attn,revidx,adj,nnodes, nrm);
  k_mcf<<<8,1024,0,stream>>>(nrm,dem,inidx,invadj,nnodes, out);
  k_dual<<<64,256,0,stream>>>(dv,dem,adj,nnodes, out);
}

// Round 4
// 533.531 us; speedup vs baseline: 2.1068x; 1.0776x over previous
//
#include <hip/hip_runtime.h>
#include <math.h>

#define VV 2048
#define BIGC 1e9f

__device__ __forceinline__ float wsum64(float v){
  v += __shfl_xor(v, 1, 64);
  v += __shfl_xor(v, 2, 64);
  v += __shfl_xor(v, 4, 64);
  v += __shfl_xor(v, 8, 64);
  v += __shfl_xor(v, 16, 64);
  v += __shfl_xor(v, 32, 64);
  return v;
}
// reductions within 16-lane groups (all lanes end with the group result)
__device__ __forceinline__ float gmax16(float v){
  v = fmaxf(v, __shfl_xor(v, 1, 16));
  v = fmaxf(v, __shfl_xor(v, 2, 16));
  v = fmaxf(v, __shfl_xor(v, 4, 16));
  v = fmaxf(v, __shfl_xor(v, 8, 16));
  return v;
}
__device__ __forceinline__ float gsum16(float v){
  v += __shfl_xor(v, 1, 16);
  v += __shfl_xor(v, 2, 16);
  v += __shfl_xor(v, 4, 16);
  v += __shfl_xor(v, 8, 16);
  return v;
}
__device__ __forceinline__ float sigm(float x){ return 1.f/(1.f+expf(-x)); }

// ---------------- K_init: zero out + masked-edge constants ----------------
// C layout: [0:64) s1m | [64:128) h2m | [128] sh2m | [384:448) s2m | [448] nwm
__global__ void k_init(const float* __restrict__ gatW, const float* __restrict__ gatb,
                       const float* __restrict__ gata, const float* __restrict__ gruWh,
                       const float* __restrict__ grub,
                       const float* __restrict__ dW1, const float* __restrict__ db1,
                       const float* __restrict__ dW2, const float* __restrict__ db2,
                       float* __restrict__ out, float* __restrict__ C)
{
  int lane = threadIdx.x;   // 64 threads
  if(lane < 8) out[lane] = 0.f;
  float gb0 = grub[lane], gb1 = grub[64+lane], gb2 = grub[128+lane];
  float z1 = sigm(gb0);
  float s1m = (1.f - z1)*tanhf(gb2);
  C[lane] = s1m;
  float acc = gatb[lane];
  for(int k=0;k<64;k++) acc += __shfl(s1m,k,64)*gatW[k*64+lane];
  float h2m = tanhf(acc);
  C[64+lane] = h2m;
  float s = wsum64(h2m*gata[lane]);
  if(lane==0) C[128] = s;
  float hm[3];
  for(int j=0;j<3;j++){
    float a2 = 0.f;
    for(int k=0;k<64;k++) a2 += __shfl(s1m,k,64)*gruWh[k*192+64*j+lane];
    hm[j] = a2;
  }
  float z2 = sigm(gb0 + hm[0]);
  float r2 = sigm(gb1 + hm[1]);
  float c2 = tanhf(gb2 + r2*hm[2]);
  float s2m = z2*s1m + (1.f-z2)*c2;
  C[384+lane] = s2m;
  int h = lane & 31;
  float a3 = 0.f;
  for(int k=0;k<64;k++) a3 += __shfl(s2m,k,64)*dW1[k*32+h];
  float t = tanhf(a3 + db1[h]);
  float p = (lane < 32) ? t*dW2[h] : 0.f;
  p = wsum64(p);
  if(lane==0) C[448] = p + db2[0];
}

// XCD-aware row base for 1024-block kernels: batch = blk&7 (tracks XCD),
// slot = blk>>3 covers 128 slots * 16 rows = 2048 rows per batch.
__device__ __forceinline__ int xcd_base(int blk, int wid){
  int b = blk & 7, slot = blk >> 3;
  return b*VV + slot*16 + wid*4;
}

// ---------------- K_enc: per-node encoder + H1/sH1. 4 rows/wave ----------------
__global__ void __launch_bounds__(256,4)
k_enc(const float* __restrict__ feat, const float* __restrict__ emb,
      const float* __restrict__ encW, const float* __restrict__ encb,
      const float* __restrict__ gatW, const float* __restrict__ gatb,
      const float* __restrict__ gata,
      float* __restrict__ enc, float* __restrict__ HH,
      float* __restrict__ sHH)
{
  __shared__ float IN[4][192];
  __shared__ float E[4][256];
  int wid = threadIdx.x >> 6, lane = threadIdx.x & 63;
  int base = xcd_base(blockIdx.x, wid);
  #pragma unroll
  for(int r=0;r<4;r++){
    int row = base+r; int u = row & (VV-1);
    float ev = (lane < 32) ? emb[u*32 + lane] : 0.f;
    float ss = wsum64(ev*ev);
    float scale = (ss > 1.f) ? 1.f/sqrtf(ss) : 1.f;
    if(lane < 32) IN[wid][r*48+lane] = ev*scale;
    else if(lane < 48) IN[wid][r*48+lane] = feat[row*16 + (lane-32)];
  }
  float acc[4];
  #pragma unroll
  for(int r=0;r<4;r++) acc[r] = encb[lane];
  for(int k=0;k<48;k++){
    float wv = encW[k*64+lane];
    #pragma unroll
    for(int r=0;r<4;r++) acc[r] += IN[wid][r*48+k]*wv;
  }
  #pragma unroll
  for(int r=0;r<4;r++){
    enc[(base+r)*64+lane] = acc[r];
    E[wid][r*64+lane] = acc[r];
  }
  float h[4];
  #pragma unroll
  for(int r=0;r<4;r++) h[r] = gatb[lane];
  for(int k=0;k<64;k++){
    float wv = gatW[k*64+lane];
    #pragma unroll
    for(int r=0;r<4;r++) h[r] += E[wid][r*64+k]*wv;
  }
  float gal = gata[lane];
  #pragma unroll
  for(int r=0;r<4;r++){
    float hv = tanhf(h[r]);
    HH[(base+r)*64+lane] = hv;
    float s = wsum64(hv*gal);
    if(lane==0) sHH[base+r] = s;
  }
}

// Edge-parallel GAT aggregation for one row. Returns agg (per-lane f).
// hmask = per-lane-f masked h row, smask = masked score.
__device__ __forceinline__ float gat_agg(
    int row, int bofs, int nn, float hmask, float smask,
    const float* __restrict__ HH, const float* __restrict__ sHH,
    const int* __restrict__ adj)
{
  int ed = threadIdx.x & 15;
  int a16 = adj[row*16 + ed];                // 1 load, 4 dup groups
  bool m16 = (a16 == nn);
  float sraw = m16 ? smask : sHH[bofs + a16];  // 1 gather
  float mx = gmax16(sraw);
  float e = expf(sraw - mx);
  float den = gsum16(e);
  float p = e/den;
  // prefetch 16 neighbor rows (independent loads)
  float hr[16];
  #pragma unroll
  for(int d=0; d<16; d++){
    int a_d = __shfl(a16, d, 16);
    hr[d] = (a_d == nn) ? hmask : HH[(bofs + a_d)*64 + (threadIdx.x & 63)];
  }
  float agg = 0.f;
  #pragma unroll
  for(int d=0; d<16; d++){
    float w = __shfl(p, d, 16);
    agg += w*hr[d];
  }
  return agg;
}

// ---------------- K_layer1: GAT1 agg + GRU1 + H2/sH2. 4 rows/wave ----------------
__global__ void __launch_bounds__(256,4)
k_layer1(const float* __restrict__ enc, const float* __restrict__ HH1,
         const float* __restrict__ sHH1,
         const float* __restrict__ gatW, const float* __restrict__ gatb,
         const float* __restrict__ gata,
         const float* __restrict__ gruWx, const float* __restrict__ gruWh,
         const float* __restrict__ grub,
         const int* __restrict__ adj, const int* __restrict__ num_nodes,
         float* __restrict__ S1, float* __restrict__ HH2,
         float* __restrict__ sHH2)
{
  __shared__ float LX[4][256];
  __shared__ float LE[4][256];
  __shared__ float LS[4][256];
  int wid = threadIdx.x>>6, lane = threadIdx.x & 63;
  int base = xcd_base(blockIdx.x, wid);
  int b = base >> 11;
  int bofs = b << 11;
  int nn = num_nodes[b];
  float tb = tanhf(gatb[lane]);           // h row for masked (state=0)
  float gal = gata[lane];
  float cs = wsum64(tb*gal);
  float e[4];
  #pragma unroll
  for(int r=0;r<4;r++){
    int row = base+r;
    float agg = gat_agg(row, bofs, nn, tb, cs - BIGC, HH1, sHH1, adj);
    e[r] = enc[row*64+lane];
    LX[wid][r*64+lane] = agg + e[r];
    LE[wid][r*64+lane] = e[r];
  }
  float ax[4][3], ah[4][3];
  #pragma unroll
  for(int r=0;r<4;r++)
    #pragma unroll
    for(int j=0;j<3;j++){ ax[r][j]=0.f; ah[r][j]=0.f; }
  for(int k=0;k<64;k++){
    float bx[4], be[4];
    #pragma unroll
    for(int r=0;r<4;r++){ bx[r]=LX[wid][r*64+k]; be[r]=LE[wid][r*64+k]; }
    #pragma unroll
    for(int j=0;j<3;j++){
      float wx = gruWx[k*192+64*j+lane];
      float wh = gruWh[k*192+64*j+lane];
      #pragma unroll
      for(int r=0;r<4;r++){ ax[r][j] += bx[r]*wx; ah[r][j] += be[r]*wh; }
    }
  }
  float gb0 = grub[lane], gb1 = grub[64+lane], gb2 = grub[128+lane];
  #pragma unroll
  for(int r=0;r<4;r++){
    float z = sigm(ax[r][0]+gb0+ah[r][0]);
    float rr = sigm(ax[r][1]+gb1+ah[r][1]);
    float c = tanhf(ax[r][2]+gb2+rr*ah[r][2]);
    float s1 = z*e[r] + (1.f-z)*c;
    S1[(base+r)*64+lane] = s1;
    LS[wid][r*64+lane] = s1;
  }
  float h[4];
  #pragma unroll
  for(int r=0;r<4;r++) h[r] = gatb[lane];
  for(int k=0;k<64;k++){
    float wv = gatW[k*64+lane];
    #pragma unroll
    for(int r=0;r<4;r++) h[r] += LS[wid][r*64+k]*wv;
  }
  #pragma unroll
  for(int r=0;r<4;r++){
    float hv = tanhf(h[r]);
    HH2[(base+r)*64+lane] = hv;
    float s = wsum64(hv*gal);
    if(lane==0) sHH2[base+r] = s;
  }
}

// ---------------- K_layer2: GAT2 agg + GRU2 + decoder. 4 rows/wave ----------------
__global__ void __launch_bounds__(256,4)
k_layer2(const float* __restrict__ enc, const float* __restrict__ HH2,
         const float* __restrict__ sHH2, const float* __restrict__ C,
         const float* __restrict__ gata,
         const float* __restrict__ gruWx, const float* __restrict__ gruWh,
         const float* __restrict__ grub,
         const float* __restrict__ dW1, const float* __restrict__ db1,
         const float* __restrict__ dW2, const float* __restrict__ db2,
         const int* __restrict__ adj, const int* __restrict__ num_nodes,
         const float* __restrict__ S1,
         float* __restrict__ S2, float* __restrict__ nwn)
{
  __shared__ float LX[4][256];
  __shared__ float LS1[4][256];
  __shared__ float LS2[4][256];
  int wid = threadIdx.x>>6, lane = threadIdx.x & 63;
  int base = xcd_base(blockIdx.x, wid);
  int b = base >> 11;
  int bofs = b << 11;
  int nn = num_nodes[b];
  float h2m = C[64+lane];
  float sh2m = C[128];
  float s1v[4];
  #pragma unroll
  for(int r=0;r<4;r++){
    int row = base+r;
    float agg = gat_agg(row, bofs, nn, h2m, sh2m - BIGC, HH2, sHH2, adj);
    float x = agg + enc[row*64+lane];
    s1v[r] = S1[row*64+lane];
    LX[wid][r*64+lane] = x;
    LS1[wid][r*64+lane] = s1v[r];
  }
  float ax[4][3], am[4][3];
  #pragma unroll
  for(int r=0;r<4;r++)
    #pragma unroll
    for(int j=0;j<3;j++){ ax[r][j]=0.f; am[r][j]=0.f; }
  for(int k=0;k<64;k++){
    float bx[4], bs[4];
    #pragma unroll
    for(int r=0;r<4;r++){ bx[r]=LX[wid][r*64+k]; bs[r]=LS1[wid][r*64+k]; }
    #pragma unroll
    for(int j=0;j<3;j++){
      float wx = gruWx[k*192+64*j+lane];
      float wh = gruWh[k*192+64*j+lane];
      #pragma unroll
      for(int r=0;r<4;r++){ ax[r][j] += bx[r]*wx; am[r][j] += bs[r]*wh; }
    }
  }
  float gb0 = grub[lane], gb1 = grub[64+lane], gb2 = grub[128+lane];
  #pragma unroll
  for(int r=0;r<4;r++){
    float z = sigm(ax[r][0]+gb0+am[r][0]);
    float rr = sigm(ax[r][1]+gb1+am[r][1]);
    float c = tanhf(ax[r][2]+gb2+rr*am[r][2]);
    float s2 = z*s1v[r] + (1.f-z)*c;
    S2[(base+r)*64+lane] = s2;
    LS2[wid][r*64+lane] = s2;
  }
  // decoder
  int h = lane & 31;
  float accd[4];
  #pragma unroll
  for(int r=0;r<4;r++) accd[r]=0.f;
  for(int k=0;k<64;k++){
    float wv = dW1[k*32+h];
    #pragma unroll
    for(int r=0;r<4;r++) accd[r] += LS2[wid][r*64+k]*wv;
  }
  float b1 = db1[h], w2 = dW2[h], b2 = db2[0];
  #pragma unroll
  for(int r=0;r<4;r++){
    float t = tanhf(accd[r] + b1);
    float p = (lane<32) ? t*w2 : 0.f;
    p = wsum64(p);
    if(lane==0) nwn[base+r] = p + b2;
  }
}

// ---------------- K_tail: node_states gather + dual head + nw gather ----------------
__global__ void __launch_bounds__(256,4)
k_tail(const float* __restrict__ S2, const float* __restrict__ nwn,
       const float* __restrict__ C,
       const float* __restrict__ uW1, const float* __restrict__ ub1,
       const float* __restrict__ uW2, const float* __restrict__ ub2,
       const int* __restrict__ adj, const int* __restrict__ num_nodes,
       float* __restrict__ nw, float* __restrict__ dv)
{
  __shared__ float LN[4][256];
  int wid = threadIdx.x>>6, lane = threadIdx.x&63;
  int base = xcd_base(blockIdx.x, wid);
  int b = base>>11;
  int bofs = b<<11;
  int nn = num_nodes[b];
  float s2m = C[384+lane];
  float nwm = C[448];
  #pragma unroll
  for(int r=0;r<4;r++){
    int row = base+r;
    int ed = lane & 15;
    int a16 = adj[row*16 + ed];
    float hr[16];
    #pragma unroll
    for(int d=0;d<16;d++){
      int a_d = __shfl(a16, d, 16);
      hr[d] = (a_d==nn) ? s2m : S2[(bofs+a_d)*64+lane];
    }
    float ns = 0.f;
    #pragma unroll
    for(int d=0;d<16;d++) ns += hr[d];
    LN[wid][r*64+lane] = ns;
    if(lane < 16){
      bool m = (a16==nn);
      nw[row*16+lane] = m ? nwm : nwn[bofs+a16];
    }
  }
  int h = lane & 31;
  float acc[4];
  #pragma unroll
  for(int r=0;r<4;r++) acc[r]=0.f;
  for(int k=0;k<64;k++){
    float wv = uW1[k*32+h];
    #pragma unroll
    for(int r=0;r<4;r++) acc[r] += LN[wid][r*64+k]*wv;
  }
  float b1 = ub1[h], w2 = uW2[h], b2 = ub2[0];
  #pragma unroll
  for(int r=0;r<4;r++){
    float t = tanhf(acc[r] + b1);
    float p = (lane<32) ? t*w2 : 0.f;
    p = wsum64(p);
    if(lane==0) dv[base+r] = p + b2;
  }
}

// ---------------- K5: incoming gather + softmax(in). 64 blocks, XCD-batched ----------------
__global__ void k_attn_in(const float* __restrict__ nw, const int* __restrict__ in_idx,
                          const int* __restrict__ inv_adj, const int* __restrict__ num_nodes,
                          float* __restrict__ attn_in)
{
  int b = blockIdx.x & 7, slot = blockIdx.x >> 3;
  int gid = b*VV + slot*256 + threadIdx.x;
  int nn = num_nodes[b];
  const float* nwb = nw + b*32768;
  float sc[16];
  int base = gid*16;
  #pragma unroll
  for(int d=0;d<16;d++){
    int ii = in_idx[base+d];
    float w = nwb[ii];
    bool im = (inv_adj[base+d]==nn);
    sc[d] = w - (im ? BIGC : 0.f);
  }
  float mx=sc[0];
  #pragma unroll
  for(int d=1;d<16;d++) mx=fmaxf(mx,sc[d]);
  float den=0.f;
  #pragma unroll
  for(int d=0;d<16;d++){sc[d]=expf(sc[d]-mx); den+=sc[d];}
  float inv=1.f/den;
  #pragma unroll
  for(int d=0;d<16;d++) attn_in[base+d] = sc[d]*inv;
}

// ---------------- K6: rev gather + softmax -> normalized ----------------
__global__ void k_norm(const float* __restrict__ attn_in, const int* __restrict__ rev_idx,
                       const int* __restrict__ adj, const int* __restrict__ num_nodes,
                       float* __restrict__ normalized)
{
  int b = blockIdx.x & 7, slot = blockIdx.x >> 3;
  int gid = b*VV + slot*256 + threadIdx.x;
  int nn = num_nodes[b];
  const float* ab = attn_in + b*32768;
  int base=gid*16;
  float sc[16];
  #pragma unroll
  for(int d=0;d<16;d++){
    float g = ab[rev_idx[base+d]];
    bool m = (adj[base+d]==nn);
    sc[d] = g - (m?BIGC:0.f);
  }
  float mx=sc[0];
  #pragma unroll
  for(int d=1;d<16;d++) mx=fmaxf(mx,sc[d]);
  float den=0.f;
  #pragma unroll
  for(int d=0;d<16;d++){sc[d]=expf(sc[d]-mx); den+=sc[d];}
  float inv=1.f/den;
  #pragma unroll
  for(int d=0;d<16;d++) normalized[base+d]=sc[d]*inv;
}

// ---------------- K7: MCF via per-node scalar iteration in LDS ----------------
__global__ void k_mcf(const float* __restrict__ normalized, const float* __restrict__ demands,
                      const int* __restrict__ in_idx, const int* __restrict__ inv_adj,
                      const int* __restrict__ num_nodes,
                      float* __restrict__ out)
{
  __shared__ float T[2][2048];
  int b = blockIdx.x; int tid = threadIdx.x;  // 1024 threads
  int nn = num_nodes[b];
  const float* nb = normalized + b*32768;
  const int* ib  = in_idx + b*32768;
  const int* vb  = inv_adj + b*32768;
  float sup[2], q[2];
  float w[2][16]; int src[2][16];
  #pragma unroll
  for(int s=0;s<2;s++){
    int vi = tid + s*1024;
    float dm = demands[b*2048+vi];
    sup[s] = fmaxf(-dm, 0.f);
    float qq = 0.f;
    #pragma unroll
    for(int d=0;d<16;d++){
      float nv = nb[vi*16+d];
      qq += nv*nv;
    }
    q[s] = qq;
    #pragma unroll
    for(int d=0;d<16;d++){
      int ii = ib[vi*16+d];
      bool im = (vb[vi*16+d]==nn);
      w[s][d] = im ? 0.f : nb[ii];
      src[s][d] = ii >> 4;
    }
    T[0][vi] = sup[s];
  }
  __syncthreads();
  int cur = 0;
  for(int it=0; it<10; ++it){
    float nt[2];
    #pragma unroll
    for(int s=0;s<2;s++){
      float acc = sup[s];
      #pragma unroll
      for(int d=0;d<16;d++) acc += w[s][d]*T[cur][src[s][d]];
      nt[s] = acc;
    }
    #pragma unroll
    for(int s=0;s<2;s++) T[cur^1][tid+s*1024] = nt[s];
    __syncthreads();
    cur ^= 1;
  }
  float fc = q[0]*T[cur][tid]*T[cur][tid] + q[1]*T[cur][tid+1024]*T[cur][tid+1024];
  fc = wsum64(fc);
  __shared__ float red[16];
  int wid = tid>>6, lane = tid&63;
  if(lane==0) red[wid]=fc;
  __syncthreads();
  if(tid==0){
    float s=0.f;
    for(int i=0;i<16;i++) s+=red[i];
    atomicAdd(out+b, s);
  }
}

// ---------------- K8: dual iterations + dual_cost contribution ----------------
__global__ void k_dual(const float* __restrict__ dual_vars, const float* __restrict__ demands,
                       const int* __restrict__ adj, const int* __restrict__ num_nodes,
                       float* __restrict__ out)
{
  int b = blockIdx.x & 7, slot = blockIdx.x >> 3;
  int gid = b*VV + slot*256 + threadIdx.x;
  int nn = num_nodes[b];
  float dvv = dual_vars[gid];
  float contrib = dvv * demands[gid];      // + dual_demand part
  #pragma unroll
  for(int d=0;d<16;d++){
    int a = adj[gid*16+d];
    bool m = (a==nn);
    float dvn = dual_vars[(b<<11)+a];
    float dd = m ? (-dvv) : dvn;           // (1-m)*dvn - m*dv
    float valid = m ? 0.f : 1.f;
    float f=0.f, acc=0.f;
    #pragma unroll
    for(int it=0; it<10; ++it){
      float grad = 2.f*f + dd;
      acc = 0.9f*acc + 0.01f*grad;
      f = fmaxf(f-acc, 0.f)*valid;
    }
    contrib -= (f*f + dd*f);              // -X part
  }
  float s = wsum64(contrib);
  __shared__ float red[4];
  int wid = threadIdx.x>>6, lane = threadIdx.x&63;
  if(lane==0) red[wid]=s;
  __syncthreads();
  if(threadIdx.x==0) atomicAdd(out+b, red[0]+red[1]+red[2]+red[3]);
}

extern "C" void kernel_launch(void* const* d_in, const int* in_sizes, int n_in,
                              void* d_out, int out_size, void* d_ws, size_t ws_size,
                              hipStream_t stream)
{
  const float* feat = (const float*)d_in[0];
  const float* dem  = (const float*)d_in[1];
  const float* emb  = (const float*)d_in[2];
  const float* encW = (const float*)d_in[3];
  const float* encb = (const float*)d_in[4];
  const float* gatW = (const float*)d_in[5];
  const float* gatb = (const float*)d_in[6];
  const float* gata = (const float*)d_in[7];
  const float* gruWx= (const float*)d_in[8];
  const float* gruWh= (const float*)d_in[9];
  const float* grub = (const float*)d_in[10];
  const float* dW1  = (const float*)d_in[11];
  const float* db1  = (const float*)d_in[12];
  const float* dW2  = (const float*)d_in[13];
  const float* db2  = (const float*)d_in[14];
  const float* uW1  = (const float*)d_in[15];
  const float* ub1  = (const float*)d_in[16];
  const float* uW2  = (const float*)d_in[17];
  const float* ub2  = (const float*)d_in[18];
  const int* adj    = (const int*)d_in[19];
  const int* invadj = (const int*)d_in[20];
  const int* inidx  = (const int*)d_in[21];
  const int* revidx = (const int*)d_in[22];
  const int* nnodes = (const int*)d_in[23];
  float* out = (float*)d_out;

  float* ws = (float*)d_ws;
  size_t off=0;
  float* enc  = ws+off; off += (size_t)16384*64;
  float* HH1  = ws+off; off += (size_t)16384*64;
  float* sHH1 = ws+off; off += (size_t)16384;
  float* S1   = ws+off; off += (size_t)16384*64;
  float* HH2  = ws+off; off += (size_t)16384*64;
  float* sHH2 = ws+off; off += (size_t)16384;
  float* S2   = ws+off; off += (size_t)16384*64;
  float* nwn  = ws+off; off += (size_t)16384;
  float* C    = ws+off; off += (size_t)512;
  float* nwb  = ws+off; off += (size_t)16384*16;
  float* attn = ws+off; off += (size_t)16384*16;
  float* nrm  = ws+off; off += (size_t)16384*16;
  float* dv   = ws+off; off += (size_t)16384;
  (void)ws_size; (void)in_sizes; (void)n_in; (void)out_size;

  k_init<<<1,64,0,stream>>>(gatW,gatb,gata,gruWh,grub,dW1,db1,dW2,db2, out,C);
  k_enc<<<1024,256,0,stream>>>(feat,emb,encW,encb,gatW,gatb,gata, enc,HH1,sHH1);
  k_layer1<<<1024,256,0,stream>>>(enc,HH1,sHH1,gatW,gatb,gata,gruWx,gruWh,grub,adj,nnodes, S1,HH2,sHH2);
  k_layer2<<<1024,256,0,stream>>>(enc,HH2,sHH2,C,gata,gruWx,gruWh,grub,dW1,db1,dW2,db2,adj,nnodes,S1, S2,nwn);
  k_tail<<<1024,256,0,stream>>>(S2,nwn,C,uW1,ub1,uW2,ub2,adj,nnodes, nwb,dv);
  k_attn_in<<<64,256,0,stream>>>(nwb,inidx,invadj,nnodes, attn);
  k_norm<<<64,256,0,stream>>>(attn,revidx,adj,nnodes, nrm);
  k_mcf<<<8,1024,0,stream>>>(nrm,dem,inidx,invadj,nnodes, out);
  k_dual<<<64,256,0,stream>>>(dv,dem,adj,nnodes, out);
}

// Round 5
// 373.679 us; speedup vs baseline: 3.0080x; 1.4278x over previous
//
#include <hip/hip_runtime.h>
#include <math.h>

#define VV 2048
#define BIGC 1e9f

__device__ __forceinline__ float wsum64(float v){
  v += __shfl_xor(v, 1, 64);
  v += __shfl_xor(v, 2, 64);
  v += __shfl_xor(v, 4, 64);
  v += __shfl_xor(v, 8, 64);
  v += __shfl_xor(v, 16, 64);
  v += __shfl_xor(v, 32, 64);
  return v;
}
__device__ __forceinline__ float gmax16(float v){
  v = fmaxf(v, __shfl_xor(v, 1, 16));
  v = fmaxf(v, __shfl_xor(v, 2, 16));
  v = fmaxf(v, __shfl_xor(v, 4, 16));
  v = fmaxf(v, __shfl_xor(v, 8, 16));
  return v;
}
__device__ __forceinline__ float gsum16(float v){
  v += __shfl_xor(v, 1, 16);
  v += __shfl_xor(v, 2, 16);
  v += __shfl_xor(v, 4, 16);
  v += __shfl_xor(v, 8, 16);
  return v;
}
__device__ __forceinline__ float sigm(float x){ return 1.f/(1.f+expf(-x)); }

// ---------------- K_init: zero out + masked-edge constants (4 waves parallel) ----------------
// C layout: [0:64) s1m | [64:128) h2m | [128] sh2m | [384:448) s2m | [448] nwm
__global__ void k_init(const float* __restrict__ gatW, const float* __restrict__ gatb,
                       const float* __restrict__ gata, const float* __restrict__ gruWh,
                       const float* __restrict__ grub,
                       const float* __restrict__ dW1, const float* __restrict__ db1,
                       const float* __restrict__ dW2, const float* __restrict__ db2,
                       float* __restrict__ out, float* __restrict__ C)
{
  __shared__ float hmL[3][64];
  int w = threadIdx.x >> 6, lane = threadIdx.x & 63;
  if(threadIdx.x < 8) out[threadIdx.x] = 0.f;
  float gb0 = grub[lane], gb1 = grub[64+lane], gb2 = grub[128+lane];
  float z1 = sigm(gb0);
  float s1m = (1.f - z1)*tanhf(gb2);
  if(w==0){
    C[lane] = s1m;
    float acc = gatb[lane];
    for(int k=0;k<64;k++) acc += __shfl(s1m,k,64)*gatW[k*64+lane];
    float h2m = tanhf(acc);
    C[64+lane] = h2m;
    float s = wsum64(h2m*gata[lane]);
    if(lane==0) C[128] = s;
  } else {
    int j = w-1;
    float a2 = 0.f;
    for(int k=0;k<64;k++) a2 += __shfl(s1m,k,64)*gruWh[k*192+64*j+lane];
    hmL[j][lane] = a2;
  }
  __syncthreads();
  if(w==0){
    float z2 = sigm(gb0 + hmL[0][lane]);
    float r2 = sigm(gb1 + hmL[1][lane]);
    float c2 = tanhf(gb2 + r2*hmL[2][lane]);
    float s2m = z2*s1m + (1.f-z2)*c2;
    C[384+lane] = s2m;
    int h = lane & 31;
    float a3 = 0.f;
    for(int k=0;k<64;k++) a3 += __shfl(s2m,k,64)*dW1[k*32+h];
    float t = tanhf(a3 + db1[h]);
    float p = (lane < 32) ? t*dW2[h] : 0.f;
    p = wsum64(p);
    if(lane==0) C[448] = p + db2[0];
  }
}

// XCD-aware row base for 512-block kernels (8 rows/wave, 4 waves):
// batch = blk&7 (tracks XCD round-robin), slot = blk>>3 in [0,64), 32 rows/block.
__device__ __forceinline__ int xcd_base8(int blk, int wid){
  int b = blk & 7, slot = blk >> 3;
  return b*VV + slot*32 + wid*8;
}

// ---------------- K_enc: per-node encoder + H1/sH1. 8 rows/wave ----------------
__global__ void __launch_bounds__(256,2)
k_enc(const float* __restrict__ feat, const float* __restrict__ emb,
      const float* __restrict__ encW, const float* __restrict__ encb,
      const float* __restrict__ gatW, const float* __restrict__ gatb,
      const float* __restrict__ gata,
      float* __restrict__ enc, float* __restrict__ HH,
      float* __restrict__ sHH)
{
  __shared__ float IN[4][384];
  __shared__ float E[4][512];
  int wid = threadIdx.x >> 6, lane = threadIdx.x & 63;
  int base = xcd_base8(blockIdx.x, wid);
  #pragma unroll
  for(int r=0;r<8;r++){
    int row = base+r; int u = row & (VV-1);
    float ev = (lane < 32) ? emb[u*32 + lane] : 0.f;
    float ss = wsum64(ev*ev);
    float scale = (ss > 1.f) ? 1.f/sqrtf(ss) : 1.f;
    if(lane < 32) IN[wid][r*48+lane] = ev*scale;
    else if(lane < 48) IN[wid][r*48+lane] = feat[row*16 + (lane-32)];
  }
  float acc[8];
  #pragma unroll
  for(int r=0;r<8;r++) acc[r] = encb[lane];
  for(int k=0;k<48;k++){
    float wv = encW[k*64+lane];
    #pragma unroll
    for(int r=0;r<8;r++) acc[r] += IN[wid][r*48+k]*wv;
  }
  #pragma unroll
  for(int r=0;r<8;r++){
    enc[(base+r)*64+lane] = acc[r];
    E[wid][r*64+lane] = acc[r];
  }
  float h[8];
  #pragma unroll
  for(int r=0;r<8;r++) h[r] = gatb[lane];
  for(int k=0;k<64;k++){
    float wv = gatW[k*64+lane];
    #pragma unroll
    for(int r=0;r<8;r++) h[r] += E[wid][r*64+k]*wv;
  }
  float gal = gata[lane];
  #pragma unroll
  for(int r=0;r<8;r++){
    float hv = tanhf(h[r]);
    HH[(base+r)*64+lane] = hv;
    float s = wsum64(hv*gal);
    if(lane==0) sHH[base+r] = s;
  }
}

// Edge-parallel GAT aggregation for one row (all 64 lanes; 16-lane edge groups).
__device__ __forceinline__ float gat_agg(
    int row, int bofs, int nn, float hmask, float smask,
    const float* __restrict__ HH, const float* __restrict__ sHH,
    const int* __restrict__ adj)
{
  int ed = threadIdx.x & 15;
  int a16 = adj[row*16 + ed];
  bool m16 = (a16 == nn);
  float sraw = m16 ? smask : sHH[bofs + a16];
  float mx = gmax16(sraw);
  float e = expf(sraw - mx);
  float den = gsum16(e);
  float p = e/den;
  float hr[16];
  #pragma unroll
  for(int d=0; d<16; d++){
    int a_d = __shfl(a16, d, 16);
    hr[d] = (a_d == nn) ? hmask : HH[(bofs + a_d)*64 + (threadIdx.x & 63)];
  }
  float agg = 0.f;
  #pragma unroll
  for(int d=0; d<16; d++){
    float w = __shfl(p, d, 16);
    agg += w*hr[d];
  }
  return agg;
}

// ---------------- K_layer1: GAT1 agg + GRU1 + H2/sH2. 8 rows/wave ----------------
__global__ void __launch_bounds__(256,2)
k_layer1(const float* __restrict__ enc, const float* __restrict__ HH1,
         const float* __restrict__ sHH1,
         const float* __restrict__ gatW, const float* __restrict__ gatb,
         const float* __restrict__ gata,
         const float* __restrict__ gruWx, const float* __restrict__ gruWh,
         const float* __restrict__ grub,
         const int* __restrict__ adj, const int* __restrict__ num_nodes,
         float* __restrict__ S1, float* __restrict__ HH2,
         float* __restrict__ sHH2)
{
  __shared__ float LX[4][512];
  __shared__ float LE[4][512];
  __shared__ float LS[4][512];
  int wid = threadIdx.x>>6, lane = threadIdx.x & 63;
  int base = xcd_base8(blockIdx.x, wid);
  int b = base >> 11;
  int bofs = b << 11;
  int nn = num_nodes[b];
  float tb = tanhf(gatb[lane]);
  float gal = gata[lane];
  float cs = wsum64(tb*gal);
  float e[8];
  #pragma unroll
  for(int r=0;r<8;r++){
    int row = base+r;
    float agg = gat_agg(row, bofs, nn, tb, cs - BIGC, HH1, sHH1, adj);
    e[r] = enc[row*64+lane];
    LX[wid][r*64+lane] = agg + e[r];
    LE[wid][r*64+lane] = e[r];
  }
  float ax[8][3], ah[8][3];
  #pragma unroll
  for(int r=0;r<8;r++)
    #pragma unroll
    for(int j=0;j<3;j++){ ax[r][j]=0.f; ah[r][j]=0.f; }
  for(int k=0;k<64;k++){
    float bx[8], be[8];
    #pragma unroll
    for(int r=0;r<8;r++){ bx[r]=LX[wid][r*64+k]; be[r]=LE[wid][r*64+k]; }
    #pragma unroll
    for(int j=0;j<3;j++){
      float wx = gruWx[k*192+64*j+lane];
      float wh = gruWh[k*192+64*j+lane];
      #pragma unroll
      for(int r=0;r<8;r++){ ax[r][j] += bx[r]*wx; ah[r][j] += be[r]*wh; }
    }
  }
  float gb0 = grub[lane], gb1 = grub[64+lane], gb2 = grub[128+lane];
  #pragma unroll
  for(int r=0;r<8;r++){
    float z = sigm(ax[r][0]+gb0+ah[r][0]);
    float rr = sigm(ax[r][1]+gb1+ah[r][1]);
    float c = tanhf(ax[r][2]+gb2+rr*ah[r][2]);
    float s1 = z*e[r] + (1.f-z)*c;
    S1[(base+r)*64+lane] = s1;
    LS[wid][r*64+lane] = s1;
  }
  float h[8];
  #pragma unroll
  for(int r=0;r<8;r++) h[r] = gatb[lane];
  for(int k=0;k<64;k++){
    float wv = gatW[k*64+lane];
    #pragma unroll
    for(int r=0;r<8;r++) h[r] += LS[wid][r*64+k]*wv;
  }
  #pragma unroll
  for(int r=0;r<8;r++){
    float hv = tanhf(h[r]);
    HH2[(base+r)*64+lane] = hv;
    float s = wsum64(hv*gal);
    if(lane==0) sHH2[base+r] = s;
  }
}

// ---------------- K_layer2: GAT2 agg + GRU2 + decoder. 8 rows/wave ----------------
__global__ void __launch_bounds__(256,2)
k_layer2(const float* __restrict__ enc, const float* __restrict__ HH2,
         const float* __restrict__ sHH2, const float* __restrict__ C,
         const float* __restrict__ gata,
         const float* __restrict__ gruWx, const float* __restrict__ gruWh,
         const float* __restrict__ grub,
         const float* __restrict__ dW1, const float* __restrict__ db1,
         const float* __restrict__ dW2, const float* __restrict__ db2,
         const int* __restrict__ adj, const int* __restrict__ num_nodes,
         const float* __restrict__ S1,
         float* __restrict__ S2, float* __restrict__ nwn)
{
  __shared__ float LX[4][512];
  __shared__ float LS1[4][512];
  __shared__ float LS2[4][512];
  int wid = threadIdx.x>>6, lane = threadIdx.x & 63;
  int base = xcd_base8(blockIdx.x, wid);
  int b = base >> 11;
  int bofs = b << 11;
  int nn = num_nodes[b];
  float h2m = C[64+lane];
  float sh2m = C[128];
  float s1v[8];
  #pragma unroll
  for(int r=0;r<8;r++){
    int row = base+r;
    float agg = gat_agg(row, bofs, nn, h2m, sh2m - BIGC, HH2, sHH2, adj);
    float x = agg + enc[row*64+lane];
    s1v[r] = S1[row*64+lane];
    LX[wid][r*64+lane] = x;
    LS1[wid][r*64+lane] = s1v[r];
  }
  float ax[8][3], am[8][3];
  #pragma unroll
  for(int r=0;r<8;r++)
    #pragma unroll
    for(int j=0;j<3;j++){ ax[r][j]=0.f; am[r][j]=0.f; }
  for(int k=0;k<64;k++){
    float bx[8], bs[8];
    #pragma unroll
    for(int r=0;r<8;r++){ bx[r]=LX[wid][r*64+k]; bs[r]=LS1[wid][r*64+k]; }
    #pragma unroll
    for(int j=0;j<3;j++){
      float wx = gruWx[k*192+64*j+lane];
      float wh = gruWh[k*192+64*j+lane];
      #pragma unroll
      for(int r=0;r<8;r++){ ax[r][j] += bx[r]*wx; am[r][j] += bs[r]*wh; }
    }
  }
  float gb0 = grub[lane], gb1 = grub[64+lane], gb2 = grub[128+lane];
  #pragma unroll
  for(int r=0;r<8;r++){
    float z = sigm(ax[r][0]+gb0+am[r][0]);
    float rr = sigm(ax[r][1]+gb1+am[r][1]);
    float c = tanhf(ax[r][2]+gb2+rr*am[r][2]);
    float s2 = z*s1v[r] + (1.f-z)*c;
    S2[(base+r)*64+lane] = s2;
    LS2[wid][r*64+lane] = s2;
  }
  int h = lane & 31;
  float accd[8];
  #pragma unroll
  for(int r=0;r<8;r++) accd[r]=0.f;
  for(int k=0;k<64;k++){
    float wv = dW1[k*32+h];
    #pragma unroll
    for(int r=0;r<8;r++) accd[r] += LS2[wid][r*64+k]*wv;
  }
  float b1 = db1[h], w2 = dW2[h], b2 = db2[0];
  #pragma unroll
  for(int r=0;r<8;r++){
    float t = tanhf(accd[r] + b1);
    float p = (lane<32) ? t*w2 : 0.f;
    p = wsum64(p);
    if(lane==0) nwn[base+r] = p + b2;
  }
}

// ---------------- K_tail: node_states gather + dual head + nw gather. 8 rows/wave ----------------
__global__ void __launch_bounds__(256,2)
k_tail(const float* __restrict__ S2, const float* __restrict__ nwn,
       const float* __restrict__ C,
       const float* __restrict__ uW1, const float* __restrict__ ub1,
       const float* __restrict__ uW2, const float* __restrict__ ub2,
       const int* __restrict__ adj, const int* __restrict__ num_nodes,
       float* __restrict__ nw, float* __restrict__ dv)
{
  __shared__ float LN[4][512];
  int wid = threadIdx.x>>6, lane = threadIdx.x&63;
  int base = xcd_base8(blockIdx.x, wid);
  int b = base>>11;
  int bofs = b<<11;
  int nn = num_nodes[b];
  float s2m = C[384+lane];
  float nwm = C[448];
  #pragma unroll
  for(int r=0;r<8;r++){
    int row = base+r;
    int ed = lane & 15;
    int a16 = adj[row*16 + ed];
    float hr[16];
    #pragma unroll
    for(int d=0;d<16;d++){
      int a_d = __shfl(a16, d, 16);
      hr[d] = (a_d==nn) ? s2m : S2[(bofs+a_d)*64+lane];
    }
    float ns = 0.f;
    #pragma unroll
    for(int d=0;d<16;d++) ns += hr[d];
    LN[wid][r*64+lane] = ns;
    if(lane < 16){
      bool m = (a16==nn);
      nw[row*16+lane] = m ? nwm : nwn[bofs+a16];
    }
  }
  int h = lane & 31;
  float acc[8];
  #pragma unroll
  for(int r=0;r<8;r++) acc[r]=0.f;
  for(int k=0;k<64;k++){
    float wv = uW1[k*32+h];
    #pragma unroll
    for(int r=0;r<8;r++) acc[r] += LN[wid][r*64+k]*wv;
  }
  float b1 = ub1[h], w2 = uW2[h], b2 = ub2[0];
  #pragma unroll
  for(int r=0;r<8;r++){
    float t = tanhf(acc[r] + b1);
    float p = (lane<32) ? t*w2 : 0.f;
    p = wsum64(p);
    if(lane==0) dv[base+r] = p + b2;
  }
}

// ---------------- K5: incoming gather + softmax(in). edge-parallel ----------------
__global__ void k_attn_in(const float* __restrict__ nw, const int* __restrict__ in_idx,
                          const int* __restrict__ inv_adj, const int* __restrict__ num_nodes,
                          float* __restrict__ attn_in)
{
  int b = blockIdx.x & 7, slot = blockIdx.x >> 3;
  int e = b*32768 + slot*256 + threadIdx.x;       // edge index
  int nn = num_nodes[b];
  float w = nw[b*32768 + in_idx[e]];
  bool im = (inv_adj[e]==nn);
  float sc = w - (im ? BIGC : 0.f);
  float mx = gmax16(sc);
  float ex = expf(sc-mx);
  float den = gsum16(ex);
  attn_in[e] = ex/den;
}

// ---------------- K6: rev gather + softmax -> normalized. edge-parallel ----------------
__global__ void k_norm(const float* __restrict__ attn_in, const int* __restrict__ rev_idx,
                       const int* __restrict__ adj, const int* __restrict__ num_nodes,
                       float* __restrict__ normalized)
{
  int b = blockIdx.x & 7, slot = blockIdx.x >> 3;
  int e = b*32768 + slot*256 + threadIdx.x;
  int nn = num_nodes[b];
  float g = attn_in[b*32768 + rev_idx[e]];
  bool m = (adj[e]==nn);
  float sc = g - (m ? BIGC : 0.f);
  float mx = gmax16(sc);
  float ex = expf(sc-mx);
  float den = gsum16(ex);
  normalized[e] = ex/den;
}

// ---------------- K7: MCF via per-node scalar iteration in LDS ----------------
__global__ void k_mcf(const float* __restrict__ normalized, const float* __restrict__ demands,
                      const int* __restrict__ in_idx, const int* __restrict__ inv_adj,
                      const int* __restrict__ num_nodes,
                      float* __restrict__ out)
{
  __shared__ float T[2][2048];
  int b = blockIdx.x; int tid = threadIdx.x;  // 1024 threads
  int nn = num_nodes[b];
  const float* nb = normalized + b*32768;
  const int* ib  = in_idx + b*32768;
  const int* vb  = inv_adj + b*32768;
  float sup[2], q[2];
  float w[2][16]; int src[2][16];
  #pragma unroll
  for(int s=0;s<2;s++){
    int vi = tid + s*1024;
    float dm = demands[b*2048+vi];
    sup[s] = fmaxf(-dm, 0.f);
    float qq = 0.f;
    #pragma unroll
    for(int d=0;d<16;d++){
      float nv = nb[vi*16+d];
      qq += nv*nv;
    }
    q[s] = qq;
    #pragma unroll
    for(int d=0;d<16;d++){
      int ii = ib[vi*16+d];
      bool im = (vb[vi*16+d]==nn);
      w[s][d] = im ? 0.f : nb[ii];
      src[s][d] = ii >> 4;
    }
    T[0][vi] = sup[s];
  }
  __syncthreads();
  int cur = 0;
  for(int it=0; it<10; ++it){
    float nt[2];
    #pragma unroll
    for(int s=0;s<2;s++){
      float acc = sup[s];
      #pragma unroll
      for(int d=0;d<16;d++) acc += w[s][d]*T[cur][src[s][d]];
      nt[s] = acc;
    }
    #pragma unroll
    for(int s=0;s<2;s++) T[cur^1][tid+s*1024] = nt[s];
    __syncthreads();
    cur ^= 1;
  }
  float fc = q[0]*T[cur][tid]*T[cur][tid] + q[1]*T[cur][tid+1024]*T[cur][tid+1024];
  fc = wsum64(fc);
  __shared__ float red[16];
  int wid = tid>>6, lane = tid&63;
  if(lane==0) red[wid]=fc;
  __syncthreads();
  if(tid==0){
    float s=0.f;
    for(int i=0;i<16;i++) s+=red[i];
    atomicAdd(out+b, s);
  }
}

// ---------------- K8: dual iterations. edge-parallel ----------------
__global__ void k_dual(const float* __restrict__ dual_vars, const float* __restrict__ demands,
                       const int* __restrict__ adj, const int* __restrict__ num_nodes,
                       float* __restrict__ out)
{
  int b = blockIdx.x & 7, slot = blockIdx.x >> 3;
  int e = b*32768 + slot*256 + threadIdx.x;
  int v = e >> 4;
  int nn = num_nodes[b];
  float dvv = dual_vars[v];
  int a = adj[e];
  bool m = (a==nn);
  float dvn = dual_vars[(b<<11)+a];
  float dd = m ? (-dvv) : dvn;
  float valid = m ? 0.f : 1.f;
  float f=0.f, acc=0.f;
  #pragma unroll
  for(int it=0; it<10; ++it){
    float grad = 2.f*f + dd;
    acc = 0.9f*acc + 0.01f*grad;
    f = fmaxf(f-acc, 0.f)*valid;
  }
  float contrib = -(f*f + dd*f);
  if((e & 15) == 0) contrib += dvv * demands[v];
  float s = wsum64(contrib);
  __shared__ float red[4];
  int wid = threadIdx.x>>6, lane = threadIdx.x&63;
  if(lane==0) red[wid]=s;
  __syncthreads();
  if(threadIdx.x==0) atomicAdd(out+b, red[0]+red[1]+red[2]+red[3]);
}

extern "C" void kernel_launch(void* const* d_in, const int* in_sizes, int n_in,
                              void* d_out, int out_size, void* d_ws, size_t ws_size,
                              hipStream_t stream)
{
  const float* feat = (const float*)d_in[0];
  const float* dem  = (const float*)d_in[1];
  const float* emb  = (const float*)d_in[2];
  const float* encW = (const float*)d_in[3];
  const float* encb = (const float*)d_in[4];
  const float* gatW = (const float*)d_in[5];
  const float* gatb = (const float*)d_in[6];
  const float* gata = (const float*)d_in[7];
  const float* gruWx= (const float*)d_in[8];
  const float* gruWh= (const float*)d_in[9];
  const float* grub = (const float*)d_in[10];
  const float* dW1  = (const float*)d_in[11];
  const float* db1  = (const float*)d_in[12];
  const float* dW2  = (const float*)d_in[13];
  const float* db2  = (const float*)d_in[14];
  const float* uW1  = (const float*)d_in[15];
  const float* ub1  = (const float*)d_in[16];
  const float* uW2  = (const float*)d_in[17];
  const float* ub2  = (const float*)d_in[18];
  const int* adj    = (const int*)d_in[19];
  const int* invadj = (const int*)d_in[20];
  const int* inidx  = (const int*)d_in[21];
  const int* revidx = (const int*)d_in[22];
  const int* nnodes = (const int*)d_in[23];
  float* out = (float*)d_out;

  float* ws = (float*)d_ws;
  size_t off=0;
  float* enc  = ws+off; off += (size_t)16384*64;
  float* HH1  = ws+off; off += (size_t)16384*64;
  float* sHH1 = ws+off; off += (size_t)16384;
  float* S1   = ws+off; off += (size_t)16384*64;
  float* HH2  = ws+off; off += (size_t)16384*64;
  float* sHH2 = ws+off; off += (size_t)16384;
  float* S2   = ws+off; off += (size_t)16384*64;
  float* nwn  = ws+off; off += (size_t)16384;
  float* C    = ws+off; off += (size_t)512;
  float* nwb  = ws+off; off += (size_t)16384*16;
  float* attn = ws+off; off += (size_t)16384*16;
  float* nrm  = ws+off; off += (size_t)16384*16;
  float* dv   = ws+off; off += (size_t)16384;
  (void)ws_size; (void)in_sizes; (void)n_in; (void)out_size;

  k_init<<<1,256,0,stream>>>(gatW,gatb,gata,gruWh,grub,dW1,db1,dW2,db2, out,C);
  k_enc<<<512,256,0,stream>>>(feat,emb,encW,encb,gatW,gatb,gata, enc,HH1,sHH1);
  k_layer1<<<512,256,0,stream>>>(enc,HH1,sHH1,gatW,gatb,gata,gruWx,gruWh,grub,adj,nnodes, S1,HH2,sHH2);
  k_layer2<<<512,256,0,stream>>>(enc,HH2,sHH2,C,gata,gruWx,gruWh,grub,dW1,db1,dW2,db2,adj,nnodes,S1, S2,nwn);
  k_tail<<<512,256,0,stream>>>(S2,nwn,C,uW1,ub1,uW2,ub2,adj,nnodes, nwb,dv);
  k_attn_in<<<1024,256,0,stream>>>(nwb,inidx,invadj,nnodes, attn);
  k_norm<<<1024,256,0,stream>>>(attn,revidx,adj,nnodes, nrm);
  k_mcf<<<8,1024,0,stream>>>(nrm,dem,inidx,invadj,nnodes, out);
  k_dual<<<1024,256,0,stream>>>(dv,dem,adj,nnodes, out);
}